// Round 12
// baseline (793.394 us; speedup 1.0000x reference)
//
#include <hip/hip_runtime.h>
#include <cstdint>

#define NN 20000
#define EE 320000
#define DHID 256

typedef short bf16x8 __attribute__((ext_vector_type(8)));
typedef float f32x4 __attribute__((ext_vector_type(4)));

// ---------------------------------------------------------------- utilities

__device__ __forceinline__ float b2f(unsigned short u) {
    union { unsigned int i; float f; } v;
    v.i = ((unsigned int)u) << 16;
    return v.f;
}

__device__ __forceinline__ void b2f2(unsigned int w, float& lo, float& hi) {
    union { unsigned int i; float f; } a, c;
    a.i = w << 16;
    c.i = w & 0xffff0000u;
    lo = a.f;
    hi = c.f;
}

__device__ __forceinline__ unsigned short f2b(float x) {
    union { float f; unsigned int i; } v;
    v.f = x;
    unsigned int r = (v.i + 0x7FFFu + ((v.i >> 16) & 1u)) >> 16;
    return (unsigned short)r;
}

__device__ __forceinline__ float wave_sum(float v) {
#pragma unroll
    for (int m = 1; m < 64; m <<= 1) v += __shfl_xor(v, m);
    return v;
}

__device__ __forceinline__ float quad16_sum(float v) {
#pragma unroll
    for (int m = 1; m < 16; m <<= 1) v += __shfl_xor(v, m);
    return v;
}

__device__ __forceinline__ float gelu_f(float x) {
    float z = 0.7978845608028654f * (x + 0.044715f * x * x * x);
    float e = __expf(2.0f * z);
    float t = 1.0f - 2.0f / (e + 1.0f);   // tanh(z)
    return 0.5f * x * (1.0f + t);
}

// async global->LDS, 16B per lane; lds dest is wave-uniform base (+HW lane*16)
__device__ __forceinline__ void gld16(const unsigned short* g, unsigned short* lds) {
    __builtin_amdgcn_global_load_lds((const __attribute__((address_space(1))) unsigned int*)g,
                                     (__attribute__((address_space(3))) unsigned int*)lds, 16, 0, 0);
}

// ---------------------------------------------------------------- CSR build

__global__ void hist_kernel(const int* __restrict__ edges, int* __restrict__ counts, int E_) {
    int e = blockIdx.x * 256 + threadIdx.x;
    if (e >= E_) return;
    atomicAdd(&counts[edges[e * 2]], 1);
}

__global__ __launch_bounds__(1024) void scan_block(const int* __restrict__ counts,
                                                   int* __restrict__ excl,
                                                   int* __restrict__ bsums, int n) {
    __shared__ int sd[1024];
    int tid = threadIdx.x;
    int i = blockIdx.x * 1024 + tid;
    int c = (i < n) ? counts[i] : 0;
    sd[tid] = c;
    __syncthreads();
#pragma unroll
    for (int off = 1; off < 1024; off <<= 1) {
        int v = (tid >= off) ? sd[tid - off] : 0;
        __syncthreads();
        sd[tid] += v;
        __syncthreads();
    }
    if (i < n) excl[i] = sd[tid] - c;
    if (tid == 1023) bsums[blockIdx.x] = sd[1023];
}

__global__ void scan_tops(int* __restrict__ bsums, int nb) {
    if (threadIdx.x == 0 && blockIdx.x == 0) {
        int run = 0;
        for (int i = 0; i < nb; ++i) { int t = bsums[i]; bsums[i] = run; run += t; }
    }
}

__global__ void scan_fix(const int* __restrict__ excl, const int* __restrict__ bsums,
                         int* __restrict__ indptr, int* __restrict__ cursor, int n) {
    int i = blockIdx.x * 256 + threadIdx.x;
    if (i < n) {
        int v = excl[i] + bsums[i >> 10];
        indptr[i] = v;
        cursor[i] = v;
    }
    if (i == 0) indptr[n] = EE;
}

__global__ void scatter_kernel(const int* __restrict__ edges, int* __restrict__ cursor,
                               int* __restrict__ ssrc, int E_) {
    int e = blockIdx.x * 256 + threadIdx.x;
    if (e >= E_) return;
    int dstn = edges[e * 2];
    int src  = edges[e * 2 + 1];
    int pos = atomicAdd(&cursor[dstn], 1);
    ssrc[pos] = src;
}

// ---------------------------------------------------------------- weight transpose: W (K x M) fp32 -> Wt (M x K) bf16

__global__ __launch_bounds__(256) void transpose_bf16(const float* __restrict__ W,
                                                      unsigned short* __restrict__ Wt,
                                                      int K, int M, size_t lsW, size_t lsT) {
    W  += (size_t)blockIdx.z * lsW;
    Wt += (size_t)blockIdx.z * lsT;
    __shared__ float sm[32][33];
    int m0 = blockIdx.x * 32, k0 = blockIdx.y * 32;
    int tx = threadIdx.x & 31, ty = threadIdx.x >> 5;
#pragma unroll
    for (int i = 0; i < 4; ++i)
        sm[ty + i * 8][tx] = W[(size_t)(k0 + ty + i * 8) * M + m0 + tx];
    __syncthreads();
#pragma unroll
    for (int i = 0; i < 4; ++i)
        Wt[(size_t)(m0 + ty + i * 8) * K + k0 + tx] = f2b(sm[tx][ty + i * 8]);
}

__global__ void convert_bf16(const float* __restrict__ in, unsigned short* __restrict__ out, int n4) {
    int i = blockIdx.x * 256 + threadIdx.x;
    if (i >= n4) return;
    float4 v = *(const float4*)(in + (size_t)i * 4);
    ushort4 o;
    o.x = f2b(v.x); o.y = f2b(v.y); o.z = f2b(v.z); o.w = f2b(v.w);
    *(ushort4*)(out + (size_t)i * 4) = o;
}

// ---------------------------------------------------------------- LayerNorm (plain, fp32 in -> fp32 + bf16)

__global__ __launch_bounds__(256) void ln_kernel(const float* __restrict__ X,
                                                 const float* __restrict__ g,
                                                 const float* __restrict__ b,
                                                 float* __restrict__ Y,
                                                 unsigned short* __restrict__ Yb, int nrows) {
    int row = blockIdx.x * 4 + (threadIdx.x >> 6);
    int lane = threadIdx.x & 63;
    if (row >= nrows) return;
    float4 v = *(const float4*)(X + (size_t)row * DHID + lane * 4);
    float sum = wave_sum(v.x + v.y + v.z + v.w);
    float sq  = wave_sum(v.x * v.x + v.y * v.y + v.z * v.z + v.w * v.w);
    float mean = sum * (1.0f / DHID);
    float var  = sq * (1.0f / DHID) - mean * mean;
    float r = rsqrtf(fmaxf(var, 0.0f) + 1e-3f);
    float4 gv = *(const float4*)(g + lane * 4);
    float4 bv = *(const float4*)(b + lane * 4);
    float4 o;
    o.x = (v.x - mean) * r * gv.x + bv.x;
    o.y = (v.y - mean) * r * gv.y + bv.y;
    o.z = (v.z - mean) * r * gv.z + bv.z;
    o.w = (v.w - mean) * r * gv.w + bv.w;
    *(float4*)(Y + (size_t)row * DHID + lane * 4) = o;
    ushort4 ob;
    ob.x = f2b(o.x); ob.y = f2b(o.y); ob.z = f2b(o.z); ob.w = f2b(o.w);
    *(ushort4*)(Yb + (size_t)row * DHID + lane * 4) = ob;
}

// LayerNorm fused with dense-chunk-sum + residual
__global__ __launch_bounds__(256) void ln_dense(const unsigned short* __restrict__ d,
                                                const float* __restrict__ xr,
                                                const float* __restrict__ g,
                                                const float* __restrict__ b,
                                                float* __restrict__ Y,
                                                unsigned short* __restrict__ Yb, int nrows) {
    int row = blockIdx.x * 4 + (threadIdx.x >> 6);
    int lane = threadIdx.x & 63;
    if (row >= nrows) return;
    float4 v = *(const float4*)(xr + (size_t)row * DHID + lane * 4);
#pragma unroll
    for (int c = 0; c < 4; ++c) {
        ushort4 t = *(const ushort4*)(d + (size_t)row * 1024 + c * 256 + lane * 4);
        v.x += b2f(t.x); v.y += b2f(t.y); v.z += b2f(t.z); v.w += b2f(t.w);
    }
    float sum = wave_sum(v.x + v.y + v.z + v.w);
    float sq  = wave_sum(v.x * v.x + v.y * v.y + v.z * v.z + v.w * v.w);
    float mean = sum * (1.0f / DHID);
    float var  = sq * (1.0f / DHID) - mean * mean;
    float r = rsqrtf(fmaxf(var, 0.0f) + 1e-3f);
    float4 gv = *(const float4*)(g + lane * 4);
    float4 bv = *(const float4*)(b + lane * 4);
    float4 o;
    o.x = (v.x - mean) * r * gv.x + bv.x;
    o.y = (v.y - mean) * r * gv.y + bv.y;
    o.z = (v.z - mean) * r * gv.z + bv.z;
    o.w = (v.w - mean) * r * gv.w + bv.w;
    *(float4*)(Y + (size_t)row * DHID + lane * 4) = o;
    ushort4 ob;
    ob.x = f2b(o.x); ob.y = f2b(o.y); ob.z = f2b(o.z); ob.w = f2b(o.w);
    *(ushort4*)(Yb + (size_t)row * DHID + lane * 4) = ob;
}

// final combine (no LN): hb = bf16(sum_c d + xr)
__global__ __launch_bounds__(256) void combine_final(const unsigned short* __restrict__ d,
                                                     const float* __restrict__ xr,
                                                     unsigned short* __restrict__ hb, int nrows) {
    int row = blockIdx.x * 4 + (threadIdx.x >> 6);
    int lane = threadIdx.x & 63;
    if (row >= nrows) return;
    float4 v = *(const float4*)(xr + (size_t)row * DHID + lane * 4);
#pragma unroll
    for (int c = 0; c < 4; ++c) {
        ushort4 t = *(const ushort4*)(d + (size_t)row * 1024 + c * 256 + lane * 4);
        v.x += b2f(t.x); v.y += b2f(t.y); v.z += b2f(t.z); v.w += b2f(t.w);
    }
    ushort4 ob;
    ob.x = f2b(v.x); ob.y = f2b(v.y); ob.z = f2b(v.z); ob.w = f2b(v.w);
    *(ushort4*)(hb + (size_t)row * DHID + lane * 4) = ob;
}

// ---------------------------------------------------------------- MFMA GEMM, 128x128 tile (R8-exact: separate Cs, 3 blocks/CU)
// EP: 0 = fp32 out (+bias), 1 = bf16 out, 2 = bf16 gelu(acc + bias)

#define CS_STRIDE 140  // 128 + 12 shorts

template <int EP>
__global__ __launch_bounds__(256, 3) void gemm128(const unsigned short* __restrict__ A,
                                                  const unsigned short* __restrict__ B,
                                                  const float* __restrict__ bias,
                                                  void* __restrict__ Cv, int nrows, int ncols) {
    __shared__ unsigned short As[128 * 32];
    __shared__ unsigned short Bs[128 * 32];
    __shared__ unsigned short Cs[128 * CS_STRIDE];
    const int bm = blockIdx.x * 128, bn = blockIdx.y * 128;
    if (bm >= nrows) return;  // grid-x padding
    const int tid  = threadIdx.x;
    const int w    = tid >> 6, lane = tid & 63;
    const int quad = lane >> 4, l16 = lane & 15;
    const int wm = w >> 1, wn = w & 1;

    const int srow = lane & 15;
    const int sg   = lane >> 4;
    int ga0 = min(bm + w * 32 + srow,      nrows - 1);
    int ga1 = min(bm + w * 32 + 16 + srow, nrows - 1);
    int gb0 = min(bn + w * 32 + srow,      ncols - 1);
    int gb1 = min(bn + w * 32 + 16 + srow, ncols - 1);
    const unsigned short* Ap0 = A + (size_t)ga0 * 256 + sg * 8;
    const unsigned short* Ap1 = A + (size_t)ga1 * 256 + sg * 8;
    const unsigned short* Bp0 = B + (size_t)gb0 * 256 + sg * 8;
    const unsigned short* Bp1 = B + (size_t)gb1 * 256 + sg * 8;
    unsigned short* la0 = As + (2 * w) * 512;
    unsigned short* la1 = As + (2 * w + 1) * 512;
    unsigned short* lb0 = Bs + (2 * w) * 512;
    unsigned short* lb1 = Bs + (2 * w + 1) * 512;

    f32x4 acc[4][4] = {};
    for (int k0 = 0; k0 < 256; k0 += 32) {
        gld16(Ap0 + k0, la0);
        gld16(Ap1 + k0, la1);
        gld16(Bp0 + k0, lb0);
        gld16(Bp1 + k0, lb1);
        __syncthreads();
        bf16x8 a[4], b[4];
#pragma unroll
        for (int mi = 0; mi < 4; ++mi)
            a[mi] = *(const bf16x8*)(As + (wm * 4 + mi) * 512 + quad * 128 + l16 * 8);
#pragma unroll
        for (int ni = 0; ni < 4; ++ni)
            b[ni] = *(const bf16x8*)(Bs + (wn * 4 + ni) * 512 + quad * 128 + l16 * 8);
#pragma unroll
        for (int mi = 0; mi < 4; ++mi)
#pragma unroll
            for (int ni = 0; ni < 4; ++ni)
                acc[mi][ni] = __builtin_amdgcn_mfma_f32_16x16x32_bf16(a[mi], b[ni], acc[mi][ni], 0, 0, 0);
        __syncthreads();
    }

    if (EP == 0) {
#pragma unroll
        for (int ni = 0; ni < 4; ++ni) {
            int col = bn + wn * 64 + ni * 16 + l16;
            if (col >= ncols) continue;
            float bv = bias ? bias[col] : 0.0f;
#pragma unroll
            for (int mi = 0; mi < 4; ++mi) {
#pragma unroll
                for (int r = 0; r < 4; ++r) {
                    int row = bm + wm * 64 + mi * 16 + quad * 4 + r;
                    if (row < nrows) ((float*)Cv)[(size_t)row * ncols + col] = acc[mi][ni][r] + bv;
                }
            }
        }
    } else {
#pragma unroll
        for (int ni = 0; ni < 4; ++ni) {
            int lc = wn * 64 + ni * 16 + l16;
            float bv = (EP == 2) ? bias[bn + lc] : 0.0f;
#pragma unroll
            for (int mi = 0; mi < 4; ++mi) {
#pragma unroll
                for (int r = 0; r < 4; ++r) {
                    int lr = wm * 64 + mi * 16 + quad * 4 + r;
                    float v = acc[mi][ni][r] + bv;
                    Cs[lr * CS_STRIDE + lc] = f2b(EP == 2 ? gelu_f(v) : v);
                }
            }
        }
        __syncthreads();
#pragma unroll
        for (int i = 0; i < 8; ++i) {
            int id = tid + 256 * i;          // 0..2047
            int lr = id >> 4;                // 0..127
            int lc = (id & 15) * 8;          // 0..120
            int grow = bm + lr;
            if (grow < nrows) {
                uint4 val = *(const uint4*)(Cs + lr * CS_STRIDE + lc);
                *(uint4*)((unsigned short*)Cv + (size_t)grow * ncols + bn + lc) = val;
            }
        }
    }
}

// ---------------------------------------------------------------- MFMA GEMM, 128x256 tile (dense only): gelu(acc+bias) -> bf16
// 2x MFMA per K-step vs gemm128 -> half the barrier drains per output element.
// grid (160, 4), ncols = 1024. LDS: As/Bs (24 KB K-loop) union Cs (64x260, epilogue).

#define CSW 260  // 256 + 4 shorts

__global__ __launch_bounds__(256, 2) void gemm256w(const unsigned short* __restrict__ A,
                                                   const unsigned short* __restrict__ B,
                                                   const float* __restrict__ bias,
                                                   unsigned short* __restrict__ Cv,
                                                   int nrows, int ncols) {
    __shared__ unsigned short smem[16640];  // max(As 4096 + Bs 8192, Cs 64*260=16640)
    unsigned short* As = smem;              // 4096 shorts (128 rows x 32 k)
    unsigned short* Bs = smem + 4096;       // 8192 shorts (256 cols x 32 k)
    unsigned short* Cs = smem;              // epilogue alias
    const int bm = blockIdx.x * 128, bn = blockIdx.y * 256;
    if (bm >= nrows) return;
    const int tid  = threadIdx.x;
    const int w    = tid >> 6, lane = tid & 63;
    const int quad = lane >> 4, l16 = lane & 15;
    const int wm = w & 1, wn = w >> 1;      // wave tile: 64 rows x 128 cols

    const int srow = lane & 15;
    const int sg   = lane >> 4;
    // A: wave stages rowgroups 2w, 2w+1 (rows w*32 .. w*32+31)
    int ga0 = min(bm + w * 32 + srow,      nrows - 1);
    int ga1 = min(bm + w * 32 + 16 + srow, nrows - 1);
    const unsigned short* Ap0 = A + (size_t)ga0 * 256 + sg * 8;
    const unsigned short* Ap1 = A + (size_t)ga1 * 256 + sg * 8;
    unsigned short* la0 = As + (2 * w) * 512;
    unsigned short* la1 = As + (2 * w + 1) * 512;
    // B: wave stages colgroups 4w..4w+3 (cols w*64 .. w*64+63)
    const unsigned short* Bp[4];
    unsigned short* lb[4];
#pragma unroll
    for (int j = 0; j < 4; ++j) {
        int gb = min(bn + w * 64 + j * 16 + srow, ncols - 1);
        Bp[j] = B + (size_t)gb * 256 + sg * 8;
        lb[j] = Bs + (4 * w + j) * 512;
    }

    f32x4 acc[4][8] = {};
    for (int k0 = 0; k0 < 256; k0 += 32) {
        gld16(Ap0 + k0, la0);
        gld16(Ap1 + k0, la1);
#pragma unroll
        for (int j = 0; j < 4; ++j) gld16(Bp[j] + k0, lb[j]);
        __syncthreads();
        bf16x8 a[4], b[8];
#pragma unroll
        for (int mi = 0; mi < 4; ++mi)
            a[mi] = *(const bf16x8*)(As + (wm * 4 + mi) * 512 + quad * 128 + l16 * 8);
#pragma unroll
        for (int ni = 0; ni < 8; ++ni)
            b[ni] = *(const bf16x8*)(Bs + (wn * 8 + ni) * 512 + quad * 128 + l16 * 8);
#pragma unroll
        for (int mi = 0; mi < 4; ++mi)
#pragma unroll
            for (int ni = 0; ni < 8; ++ni)
                acc[mi][ni] = __builtin_amdgcn_mfma_f32_16x16x32_bf16(a[mi], b[ni], acc[mi][ni], 0, 0, 0);
        __syncthreads();
    }

    // epilogue: two 64-row halves through Cs (64 x 260)
#pragma unroll
    for (int half = 0; half < 2; ++half) {
        if (wm == half) {
#pragma unroll
            for (int ni = 0; ni < 8; ++ni) {
                int lc = wn * 128 + ni * 16 + l16;
                float bv = bias[bn + lc];
#pragma unroll
                for (int mi = 0; mi < 4; ++mi) {
#pragma unroll
                    for (int r = 0; r < 4; ++r) {
                        int lr = mi * 16 + quad * 4 + r;   // 0..63
                        Cs[lr * CSW + lc] = f2b(gelu_f(acc[mi][ni][r] + bv));
                    }
                }
            }
        }
        __syncthreads();
#pragma unroll
        for (int i = 0; i < 8; ++i) {
            int id = tid + 256 * i;          // 0..2047
            int lr = id >> 5;                // 0..63
            int lc = (id & 31) * 8;          // 0..248
            int grow = bm + half * 64 + lr;
            if (grow < nrows) {
                uint4 val = *(const uint4*)(Cs + lr * CSW + lc);
                *(uint4*)(Cv + (size_t)grow * ncols + bn + lc) = val;
            }
        }
        __syncthreads();
    }
}

// ---------------------------------------------------------------- fused GAT edge phase (online softmax, pair-unrolled)

__global__ __launch_bounds__(256) void gat_fused(const unsigned short* __restrict__ zb,
                                                 const float* __restrict__ att,
                                                 const int* __restrict__ ssrc,
                                                 const int* __restrict__ indptr,
                                                 const float* __restrict__ hn,
                                                 const float* __restrict__ g,
                                                 const float* __restrict__ b,
                                                 float* __restrict__ xr,
                                                 unsigned short* __restrict__ xrb, int nrows) {
    int wid = threadIdx.x >> 6;
    int lane = threadIdx.x & 63;
    int n = blockIdx.x * 4 + wid;
    if (n >= nrows) return;
    int start = indptr[n];
    int end = indptr[n + 1];

    ushort4 zlu = *(const ushort4*)(zb + (size_t)n * 512 + lane * 4);
    float zl0 = b2f(zlu.x), zl1 = b2f(zlu.y), zl2 = b2f(zlu.z), zl3 = b2f(zlu.w);
    float4 a4 = *(const float4*)(att + lane * 4);
    size_t idx = (size_t)n * DHID + lane * 4;
    float4 rres = *(const float4*)(hn + idx);

    float m = -3.0e38f, denom = 0.f;
    float ax = 0.f, ay = 0.f, az = 0.f, aw = 0.f;

    const uint2* zrp = (const uint2*)(zb + 256);  // row n: zrp[n*128 + lane]
    uint2 c0 = make_uint2(0, 0), c1 = make_uint2(0, 0);
    if (start < end) {
        int i0 = ssrc[start];
        int i1 = ssrc[(start + 1 < end) ? start + 1 : start];
        c0 = zrp[(size_t)i0 * 128 + lane];
        c1 = zrp[(size_t)i1 * 128 + lane];
    }
    for (int p = start; p < end; p += 2) {
        uint2 u0 = c0, u1 = c1;
        bool val1 = (p + 1 < end);
        if (p + 2 < end) {
            int j0 = ssrc[p + 2];
            int j1 = ssrc[(p + 3 < end) ? p + 3 : p + 2];
            c0 = zrp[(size_t)j0 * 128 + lane];
            c1 = zrp[(size_t)j1 * 128 + lane];
        }
        float z00, z01, z02, z03, z10, z11, z12, z13;
        b2f2(u0.x, z00, z01); b2f2(u0.y, z02, z03);
        b2f2(u1.x, z10, z11); b2f2(u1.y, z12, z13);

        float v0 = zl0 + z00, v1 = zl1 + z01, v2 = zl2 + z02, v3 = zl3 + z03;
        float t0 = zl0 + z10, t1 = zl1 + z11, t2 = zl2 + z12, t3 = zl3 + z13;
        v0 = (v0 > 0.f) ? v0 : 0.2f * v0;
        v1 = (v1 > 0.f) ? v1 : 0.2f * v1;
        v2 = (v2 > 0.f) ? v2 : 0.2f * v2;
        v3 = (v3 > 0.f) ? v3 : 0.2f * v3;
        t0 = (t0 > 0.f) ? t0 : 0.2f * t0;
        t1 = (t1 > 0.f) ? t1 : 0.2f * t1;
        t2 = (t2 > 0.f) ? t2 : 0.2f * t2;
        t3 = (t3 > 0.f) ? t3 : 0.2f * t3;
        float part0 = a4.x * v0 + a4.y * v1 + a4.z * v2 + a4.w * v3;
        float part1 = a4.x * t0 + a4.y * t1 + a4.z * t2 + a4.w * t3;
        float sp0 = quad16_sum(part0);      // per-head (quad) score
        float sp1 = quad16_sum(part1);
        if (!val1) sp1 = -3.0e38f;          // sentinel: weight underflows to 0
        float newm = fmaxf(m, fmaxf(sp0, sp1));
        float corr = __expf(m - newm);      // 0 on first pair
        float w0 = __expf(sp0 - newm);
        float w1 = __expf(sp1 - newm);
        denom = denom * corr + w0 + w1;
        ax = ax * corr + w0 * z00 + w1 * z10;
        ay = ay * corr + w0 * z01 + w1 * z11;
        az = az * corr + w0 * z02 + w1 * z12;
        aw = aw * corr + w0 * z03 + w1 * z13;
        m = newm;
    }
    float inv = 1.0f / (denom + 1e-9f);
    float4 o;
    o.x = ax * inv + rres.x;
    o.y = ay * inv + rres.y;
    o.z = az * inv + rres.z;
    o.w = aw * inv + rres.w;
    float sum = wave_sum(o.x + o.y + o.z + o.w);
    float sq  = wave_sum(o.x * o.x + o.y * o.y + o.z * o.z + o.w * o.w);
    float mean = sum * (1.0f / DHID);
    float var  = sq * (1.0f / DHID) - mean * mean;
    float rr = rsqrtf(fmaxf(var, 0.0f) + 1e-3f);
    float4 gv = *(const float4*)(g + lane * 4);
    float4 bv = *(const float4*)(b + lane * 4);
    float4 y;
    y.x = (o.x - mean) * rr * gv.x + bv.x;
    y.y = (o.y - mean) * rr * gv.y + bv.y;
    y.z = (o.z - mean) * rr * gv.z + bv.z;
    y.w = (o.w - mean) * rr * gv.w + bv.w;
    *(float4*)(xr + idx) = y;
    ushort4 ob;
    ob.x = f2b(y.x); ob.y = f2b(y.y); ob.z = f2b(y.z); ob.w = f2b(y.w);
    *(ushort4*)(xrb + idx) = ob;
}

// ---------------------------------------------------------------- host

extern "C" void kernel_launch(void* const* d_in, const int* in_sizes, int n_in,
                              void* d_out, int out_size, void* d_ws, size_t ws_size,
                              hipStream_t stream) {
    const float* x       = (const float*)d_in[0];
    const float* head_W  = (const float*)d_in[1];
    const float* head_b  = (const float*)d_in[2];
    const float* ng_g    = (const float*)d_in[3];
    const float* ng_b    = (const float*)d_in[4];
    const float* Wl      = (const float*)d_in[5];
    const float* Wr      = (const float*)d_in[6];
    const float* att     = (const float*)d_in[7];
    const float* nd_g    = (const float*)d_in[8];
    const float* nd_b    = (const float*)d_in[9];
    const float* dense_W = (const float*)d_in[10];
    const float* dense_b = (const float*)d_in[11];
    const float* tail_W  = (const float*)d_in[12];
    const float* tail_b  = (const float*)d_in[13];
    const int*   edges   = (const int*)d_in[14];
    float* out = (float*)d_out;

    const size_t NH = (size_t)NN * DHID;  // 5,120,000
    // ---- workspace layout (liveness-checked; zb/d union is deliberate) ----
    float* xr = (float*)d_ws;                           // NH f32
    float* hn = xr + NH;                                // NH f32
    unsigned short* hnb = (unsigned short*)(hn + NH);   // NH bf16
    unsigned short* xrb = hnb + NH;                     // NH bf16
    unsigned short* U   = xrb + NH;                     // union region, 4*NH shorts
    unsigned short* zb  = U;                            //   N x 512 bf16  (dies at gat_fused)
    unsigned short* d_buf = U;                          //   N x 1024 bf16 (written after gat_fused)
    unsigned short* headT  = U + 4 * NH;
    unsigned short* WzT    = headT + 65536;             // 4 x (512 x 256)
    unsigned short* denseT = WzT + 524288;              // 4 x (1024 x 256)
    unsigned short* tailT  = denseT + 1048576;          // 64 x 256
    int* counts = (int*)(tailT + 16384);
    int* bsums  = counts + NN;
    int* excl   = bsums + 32;
    int* indptr = excl + NN;
    int* cursor = indptr + NN + 1;
    int* ssrc   = cursor + NN;

    // CSR build
    hipMemsetAsync(counts, 0, NN * sizeof(int), stream);
    hist_kernel<<<(EE + 255) / 256, 256, 0, stream>>>(edges, counts, EE);
    scan_block<<<(NN + 1023) / 1024, 1024, 0, stream>>>(counts, excl, bsums, NN);
    scan_tops<<<1, 64, 0, stream>>>(bsums, (NN + 1023) / 1024);
    scan_fix<<<(NN + 255) / 256, 256, 0, stream>>>(excl, bsums, indptr, cursor, NN);
    scatter_kernel<<<(EE + 255) / 256, 256, 0, stream>>>(edges, cursor, ssrc, EE);

    // weight prep
    transpose_bf16<<<dim3(8, 8, 1), 256, 0, stream>>>(head_W, headT, 256, 256, 0, 0);
    transpose_bf16<<<dim3(8, 8, 4), 256, 0, stream>>>(Wl, WzT, 256, 256, 65536, 131072);
    transpose_bf16<<<dim3(8, 8, 4), 256, 0, stream>>>(Wr, WzT + 65536, 256, 256, 65536, 131072);
    transpose_bf16<<<dim3(32, 8, 4), 256, 0, stream>>>(dense_W, denseT, 256, 1024, 262144, 262144);
    transpose_bf16<<<dim3(2, 8, 1), 256, 0, stream>>>(tail_W, tailT, 256, 64, 0, 0);
    convert_bf16<<<(int)(NH / 4 + 255) / 256, 256, 0, stream>>>(x, hnb, (int)(NH / 4));

    const int GXP = 160;  // multiple of 8 -> XCD = bx & 7 for every by
    // head: xr = x @ head_W + head_b (fp32)
    gemm128<0><<<dim3(GXP, 2), 256, 0, stream>>>(hnb, headT, head_b, xr, NN, 256);

    for (int l = 0; l < 4; ++l) {
        if (l == 0)
            ln_kernel<<<NN / 4, 256, 0, stream>>>(xr, ng_g, ng_b, hn, hnb, NN);
        else
            ln_dense<<<NN / 4, 256, 0, stream>>>(d_buf, xr, ng_g + l * 256, ng_b + l * 256, hn, hnb, NN);
        // [zl|zr] = hn @ [Wl|Wr]
        gemm128<1><<<dim3(GXP, 4), 256, 0, stream>>>(hnb, WzT + (size_t)l * 131072, nullptr, zb, NN, 512);
        // fused scores + online-softmax agg + residual + LayerNorm
        gat_fused<<<(NN + 3) / 4, 256, 0, stream>>>(zb, att + l * 256, ssrc, indptr, hn,
                                                    nd_g + l * 256, nd_b + l * 256, xr, xrb, NN);
        // d = gelu(xr @ dense_W + dense_b)  (128x256 tiles) — clobbers zb (dead)
        gemm256w<<<dim3(GXP, 4), 256, 0, stream>>>(xrb, denseT + (size_t)l * 262144,
                                                   dense_b + l * 1024, d_buf, NN, 1024);
    }
    // hb = bf16(sum_c d + xr) -> hnb (dead); out = hb @ tail_W + tail_b
    combine_final<<<NN / 4, 256, 0, stream>>>(d_buf, xr, hnb, NN);
    gemm128<0><<<dim3(GXP, 1), 256, 0, stream>>>(hnb, tailT, tail_b, out, NN, 64);
}

// Round 13
// 639.424 us; speedup vs baseline: 1.2408x; 1.2408x over previous
//
#include <hip/hip_runtime.h>
#include <cstdint>

#define NN 20000
#define EE 320000
#define DHID 256

typedef short bf16x8 __attribute__((ext_vector_type(8)));
typedef float f32x4 __attribute__((ext_vector_type(4)));

// ---------------------------------------------------------------- utilities

__device__ __forceinline__ float b2f(unsigned short u) {
    union { unsigned int i; float f; } v;
    v.i = ((unsigned int)u) << 16;
    return v.f;
}

__device__ __forceinline__ void b2f2(unsigned int w, float& lo, float& hi) {
    union { unsigned int i; float f; } a, c;
    a.i = w << 16;
    c.i = w & 0xffff0000u;
    lo = a.f;
    hi = c.f;
}

__device__ __forceinline__ unsigned short f2b(float x) {
    union { float f; unsigned int i; } v;
    v.f = x;
    unsigned int r = (v.i + 0x7FFFu + ((v.i >> 16) & 1u)) >> 16;
    return (unsigned short)r;
}

__device__ __forceinline__ float wave_sum(float v) {
#pragma unroll
    for (int m = 1; m < 64; m <<= 1) v += __shfl_xor(v, m);
    return v;
}

__device__ __forceinline__ float quad16_sum(float v) {
#pragma unroll
    for (int m = 1; m < 16; m <<= 1) v += __shfl_xor(v, m);
    return v;
}

__device__ __forceinline__ float gelu_f(float x) {
    float z = 0.7978845608028654f * (x + 0.044715f * x * x * x);
    float e = __expf(2.0f * z);
    float t = 1.0f - 2.0f / (e + 1.0f);   // tanh(z)
    return 0.5f * x * (1.0f + t);
}

// async global->LDS, 16B per lane; lds dest is wave-uniform base (+HW lane*16)
__device__ __forceinline__ void gld16(const unsigned short* g, unsigned short* lds) {
    __builtin_amdgcn_global_load_lds((const __attribute__((address_space(1))) unsigned int*)g,
                                     (__attribute__((address_space(3))) unsigned int*)lds, 16, 0, 0);
}

// ---------------------------------------------------------------- CSR build

__global__ void hist_kernel(const int* __restrict__ edges, int* __restrict__ counts, int E_) {
    int e = blockIdx.x * 256 + threadIdx.x;
    if (e >= E_) return;
    atomicAdd(&counts[edges[e * 2]], 1);
}

__global__ __launch_bounds__(1024) void scan_block(const int* __restrict__ counts,
                                                   int* __restrict__ excl,
                                                   int* __restrict__ bsums, int n) {
    __shared__ int sd[1024];
    int tid = threadIdx.x;
    int i = blockIdx.x * 1024 + tid;
    int c = (i < n) ? counts[i] : 0;
    sd[tid] = c;
    __syncthreads();
#pragma unroll
    for (int off = 1; off < 1024; off <<= 1) {
        int v = (tid >= off) ? sd[tid - off] : 0;
        __syncthreads();
        sd[tid] += v;
        __syncthreads();
    }
    if (i < n) excl[i] = sd[tid] - c;
    if (tid == 1023) bsums[blockIdx.x] = sd[1023];
}

__global__ void scan_tops(int* __restrict__ bsums, int nb) {
    if (threadIdx.x == 0 && blockIdx.x == 0) {
        int run = 0;
        for (int i = 0; i < nb; ++i) { int t = bsums[i]; bsums[i] = run; run += t; }
    }
}

__global__ void scan_fix(const int* __restrict__ excl, const int* __restrict__ bsums,
                         int* __restrict__ indptr, int* __restrict__ cursor, int n) {
    int i = blockIdx.x * 256 + threadIdx.x;
    if (i < n) {
        int v = excl[i] + bsums[i >> 10];
        indptr[i] = v;
        cursor[i] = v;
    }
    if (i == 0) indptr[n] = EE;
}

__global__ void scatter_kernel(const int* __restrict__ edges, int* __restrict__ cursor,
                               int* __restrict__ ssrc, int E_) {
    int e = blockIdx.x * 256 + threadIdx.x;
    if (e >= E_) return;
    int dstn = edges[e * 2];
    int src  = edges[e * 2 + 1];
    int pos = atomicAdd(&cursor[dstn], 1);
    ssrc[pos] = src;
}

// ---------------------------------------------------------------- weight transpose: W (K x M) fp32 -> Wt (M x K) bf16

__global__ __launch_bounds__(256) void transpose_bf16(const float* __restrict__ W,
                                                      unsigned short* __restrict__ Wt,
                                                      int K, int M, size_t lsW, size_t lsT) {
    W  += (size_t)blockIdx.z * lsW;
    Wt += (size_t)blockIdx.z * lsT;
    __shared__ float sm[32][33];
    int m0 = blockIdx.x * 32, k0 = blockIdx.y * 32;
    int tx = threadIdx.x & 31, ty = threadIdx.x >> 5;
#pragma unroll
    for (int i = 0; i < 4; ++i)
        sm[ty + i * 8][tx] = W[(size_t)(k0 + ty + i * 8) * M + m0 + tx];
    __syncthreads();
#pragma unroll
    for (int i = 0; i < 4; ++i)
        Wt[(size_t)(m0 + ty + i * 8) * K + k0 + tx] = f2b(sm[tx][ty + i * 8]);
}

__global__ void convert_bf16(const float* __restrict__ in, unsigned short* __restrict__ out, int n4) {
    int i = blockIdx.x * 256 + threadIdx.x;
    if (i >= n4) return;
    float4 v = *(const float4*)(in + (size_t)i * 4);
    ushort4 o;
    o.x = f2b(v.x); o.y = f2b(v.y); o.z = f2b(v.z); o.w = f2b(v.w);
    *(ushort4*)(out + (size_t)i * 4) = o;
}

// ---------------------------------------------------------------- LayerNorm (plain, fp32 in -> fp32 + bf16)

__global__ __launch_bounds__(256) void ln_kernel(const float* __restrict__ X,
                                                 const float* __restrict__ g,
                                                 const float* __restrict__ b,
                                                 float* __restrict__ Y,
                                                 unsigned short* __restrict__ Yb, int nrows) {
    int row = blockIdx.x * 4 + (threadIdx.x >> 6);
    int lane = threadIdx.x & 63;
    if (row >= nrows) return;
    float4 v = *(const float4*)(X + (size_t)row * DHID + lane * 4);
    float sum = wave_sum(v.x + v.y + v.z + v.w);
    float sq  = wave_sum(v.x * v.x + v.y * v.y + v.z * v.z + v.w * v.w);
    float mean = sum * (1.0f / DHID);
    float var  = sq * (1.0f / DHID) - mean * mean;
    float r = rsqrtf(fmaxf(var, 0.0f) + 1e-3f);
    float4 gv = *(const float4*)(g + lane * 4);
    float4 bv = *(const float4*)(b + lane * 4);
    float4 o;
    o.x = (v.x - mean) * r * gv.x + bv.x;
    o.y = (v.y - mean) * r * gv.y + bv.y;
    o.z = (v.z - mean) * r * gv.z + bv.z;
    o.w = (v.w - mean) * r * gv.w + bv.w;
    *(float4*)(Y + (size_t)row * DHID + lane * 4) = o;
    ushort4 ob;
    ob.x = f2b(o.x); ob.y = f2b(o.y); ob.z = f2b(o.z); ob.w = f2b(o.w);
    *(ushort4*)(Yb + (size_t)row * DHID + lane * 4) = ob;
}

// LayerNorm fused with dense-chunk-sum + residual
__global__ __launch_bounds__(256) void ln_dense(const unsigned short* __restrict__ d,
                                                const float* __restrict__ xr,
                                                const float* __restrict__ g,
                                                const float* __restrict__ b,
                                                float* __restrict__ Y,
                                                unsigned short* __restrict__ Yb, int nrows) {
    int row = blockIdx.x * 4 + (threadIdx.x >> 6);
    int lane = threadIdx.x & 63;
    if (row >= nrows) return;
    float4 v = *(const float4*)(xr + (size_t)row * DHID + lane * 4);
#pragma unroll
    for (int c = 0; c < 4; ++c) {
        ushort4 t = *(const ushort4*)(d + (size_t)row * 1024 + c * 256 + lane * 4);
        v.x += b2f(t.x); v.y += b2f(t.y); v.z += b2f(t.z); v.w += b2f(t.w);
    }
    float sum = wave_sum(v.x + v.y + v.z + v.w);
    float sq  = wave_sum(v.x * v.x + v.y * v.y + v.z * v.z + v.w * v.w);
    float mean = sum * (1.0f / DHID);
    float var  = sq * (1.0f / DHID) - mean * mean;
    float r = rsqrtf(fmaxf(var, 0.0f) + 1e-3f);
    float4 gv = *(const float4*)(g + lane * 4);
    float4 bv = *(const float4*)(b + lane * 4);
    float4 o;
    o.x = (v.x - mean) * r * gv.x + bv.x;
    o.y = (v.y - mean) * r * gv.y + bv.y;
    o.z = (v.z - mean) * r * gv.z + bv.z;
    o.w = (v.w - mean) * r * gv.w + bv.w;
    *(float4*)(Y + (size_t)row * DHID + lane * 4) = o;
    ushort4 ob;
    ob.x = f2b(o.x); ob.y = f2b(o.y); ob.z = f2b(o.z); ob.w = f2b(o.w);
    *(ushort4*)(Yb + (size_t)row * DHID + lane * 4) = ob;
}

// final combine (no LN): hb = bf16(sum_c d + xr)
__global__ __launch_bounds__(256) void combine_final(const unsigned short* __restrict__ d,
                                                     const float* __restrict__ xr,
                                                     unsigned short* __restrict__ hb, int nrows) {
    int row = blockIdx.x * 4 + (threadIdx.x >> 6);
    int lane = threadIdx.x & 63;
    if (row >= nrows) return;
    float4 v = *(const float4*)(xr + (size_t)row * DHID + lane * 4);
#pragma unroll
    for (int c = 0; c < 4; ++c) {
        ushort4 t = *(const ushort4*)(d + (size_t)row * 1024 + c * 256 + lane * 4);
        v.x += b2f(t.x); v.y += b2f(t.y); v.z += b2f(t.z); v.w += b2f(t.w);
    }
    ushort4 ob;
    ob.x = f2b(v.x); ob.y = f2b(v.y); ob.z = f2b(v.z); ob.w = f2b(v.w);
    *(ushort4*)(hb + (size_t)row * DHID + lane * 4) = ob;
}

// ---------------------------------------------------------------- MFMA GEMM, 128x128 tile, BK=64 (half the barrier drains vs BK=32)
// A: nrows x 256 bf16 (k contig); B: ncols x 256 bf16 (k contig, i.e. W^T)
// EP: 0 = fp32 out (+bias), 1 = bf16 out, 2 = bf16 gelu(acc + bias)
// Grid-x padded to multiple of 8 -> XCD = bx & 7 for all by (A fetched once).
// LDS: As/Bs (32 KB, K-loop) union Cs (128x140 = 35.8 KB, epilogue only).
// LDS layout per 16-row group: 1024 shorts; offset(row,g) = (row>>4)*1024 + g*128 + (row&15)*8, g = k-group of 8 bf16 (g in 0..7).

#define CS_STRIDE 140  // 128 + 12 shorts

template <int EP>
__global__ __launch_bounds__(256, 3) void gemm128(const unsigned short* __restrict__ A,
                                                  const unsigned short* __restrict__ B,
                                                  const float* __restrict__ bias,
                                                  void* __restrict__ Cv, int nrows, int ncols) {
    __shared__ unsigned short smem[128 * CS_STRIDE];  // 35840 B; >= As(16KB)+Bs(16KB)
    unsigned short* As = smem;                        // 8192 shorts (128 rows x 64 k)
    unsigned short* Bs = smem + 8192;                 // 8192 shorts (128 cols x 64 k)
    unsigned short* Cs = smem;                        // epilogue alias (after final barrier)
    const int bm = blockIdx.x * 128, bn = blockIdx.y * 128;
    if (bm >= nrows) return;  // grid-x padding
    const int tid  = threadIdx.x;
    const int w    = tid >> 6, lane = tid & 63;
    const int quad = lane >> 4, l16 = lane & 15;
    const int wm = w >> 1, wn = w & 1;

    const int srow = lane & 15;
    const int sg   = lane >> 4;   // 0..3
    int ga0 = min(bm + w * 32 + srow,      nrows - 1);
    int ga1 = min(bm + w * 32 + 16 + srow, nrows - 1);
    int gb0 = min(bn + w * 32 + srow,      ncols - 1);
    int gb1 = min(bn + w * 32 + 16 + srow, ncols - 1);
    const unsigned short* Ap0 = A + (size_t)ga0 * 256 + sg * 8;
    const unsigned short* Ap1 = A + (size_t)ga1 * 256 + sg * 8;
    const unsigned short* Bp0 = B + (size_t)gb0 * 256 + sg * 8;
    const unsigned short* Bp1 = B + (size_t)gb1 * 256 + sg * 8;
    unsigned short* la0 = As + (2 * w) * 1024;
    unsigned short* la1 = As + (2 * w + 1) * 1024;
    unsigned short* lb0 = Bs + (2 * w) * 1024;
    unsigned short* lb1 = Bs + (2 * w + 1) * 1024;

    f32x4 acc[4][4] = {};
    for (int k0 = 0; k0 < 256; k0 += 64) {
        // stage 64-wide K slab: 2 issues per 16-row group (g 0..3, then g 4..7)
        gld16(Ap0 + k0,      la0);
        gld16(Ap0 + k0 + 32, la0 + 512);
        gld16(Ap1 + k0,      la1);
        gld16(Ap1 + k0 + 32, la1 + 512);
        gld16(Bp0 + k0,      lb0);
        gld16(Bp0 + k0 + 32, lb0 + 512);
        gld16(Bp1 + k0,      lb1);
        gld16(Bp1 + k0 + 32, lb1 + 512);
        __syncthreads();
#pragma unroll
        for (int kk = 0; kk < 2; ++kk) {
            bf16x8 a[4], b[4];
#pragma unroll
            for (int mi = 0; mi < 4; ++mi)
                a[mi] = *(const bf16x8*)(As + (wm * 4 + mi) * 1024 + (kk * 4 + quad) * 128 + l16 * 8);
#pragma unroll
            for (int ni = 0; ni < 4; ++ni)
                b[ni] = *(const bf16x8*)(Bs + (wn * 4 + ni) * 1024 + (kk * 4 + quad) * 128 + l16 * 8);
#pragma unroll
            for (int mi = 0; mi < 4; ++mi)
#pragma unroll
                for (int ni = 0; ni < 4; ++ni)
                    acc[mi][ni] = __builtin_amdgcn_mfma_f32_16x16x32_bf16(a[mi], b[ni], acc[mi][ni], 0, 0, 0);
        }
        __syncthreads();
    }

    if (EP == 0) {
        // fp32 out (head/tail): direct stores
#pragma unroll
        for (int ni = 0; ni < 4; ++ni) {
            int col = bn + wn * 64 + ni * 16 + l16;
            if (col >= ncols) continue;
            float bv = bias ? bias[col] : 0.0f;
#pragma unroll
            for (int mi = 0; mi < 4; ++mi) {
#pragma unroll
                for (int r = 0; r < 4; ++r) {
                    int row = bm + wm * 64 + mi * 16 + quad * 4 + r;
                    if (row < nrows) ((float*)Cv)[(size_t)row * ncols + col] = acc[mi][ni][r] + bv;
                }
            }
        }
    } else {
        // bf16 out: stage tile in Cs (aliases As/Bs, dead after K-loop), coalesced 16B stores
#pragma unroll
        for (int ni = 0; ni < 4; ++ni) {
            int lc = wn * 64 + ni * 16 + l16;
            float bv = (EP == 2) ? bias[bn + lc] : 0.0f;
#pragma unroll
            for (int mi = 0; mi < 4; ++mi) {
#pragma unroll
                for (int r = 0; r < 4; ++r) {
                    int lr = wm * 64 + mi * 16 + quad * 4 + r;
                    float v = acc[mi][ni][r] + bv;
                    Cs[lr * CS_STRIDE + lc] = f2b(EP == 2 ? gelu_f(v) : v);
                }
            }
        }
        __syncthreads();
#pragma unroll
        for (int i = 0; i < 8; ++i) {
            int id = tid + 256 * i;          // 0..2047
            int lr = id >> 4;                // 0..127
            int lc = (id & 15) * 8;          // 0..120
            int grow = bm + lr;
            if (grow < nrows) {
                uint4 val = *(const uint4*)(Cs + lr * CS_STRIDE + lc);
                *(uint4*)((unsigned short*)Cv + (size_t)grow * ncols + bn + lc) = val;
            }
        }
    }
}

// ---------------------------------------------------------------- fused GAT edge phase (online softmax, pair-unrolled; VGPR 24)

__global__ __launch_bounds__(256) void gat_fused(const unsigned short* __restrict__ zb,
                                                 const float* __restrict__ att,
                                                 const int* __restrict__ ssrc,
                                                 const int* __restrict__ indptr,
                                                 const float* __restrict__ hn,
                                                 const float* __restrict__ g,
                                                 const float* __restrict__ b,
                                                 float* __restrict__ xr,
                                                 unsigned short* __restrict__ xrb, int nrows) {
    int wid = threadIdx.x >> 6;
    int lane = threadIdx.x & 63;
    int n = blockIdx.x * 4 + wid;
    if (n >= nrows) return;
    int start = indptr[n];
    int end = indptr[n + 1];

    ushort4 zlu = *(const ushort4*)(zb + (size_t)n * 512 + lane * 4);
    float zl0 = b2f(zlu.x), zl1 = b2f(zlu.y), zl2 = b2f(zlu.z), zl3 = b2f(zlu.w);
    float4 a4 = *(const float4*)(att + lane * 4);
    size_t idx = (size_t)n * DHID + lane * 4;
    float4 rres = *(const float4*)(hn + idx);

    float m = -3.0e38f, denom = 0.f;
    float ax = 0.f, ay = 0.f, az = 0.f, aw = 0.f;

    const uint2* zrp = (const uint2*)(zb + 256);  // row n: zrp[n*128 + lane]
    uint2 c0 = make_uint2(0, 0), c1 = make_uint2(0, 0);
    if (start < end) {
        int i0 = ssrc[start];
        int i1 = ssrc[(start + 1 < end) ? start + 1 : start];
        c0 = zrp[(size_t)i0 * 128 + lane];
        c1 = zrp[(size_t)i1 * 128 + lane];
    }
    for (int p = start; p < end; p += 2) {
        uint2 u0 = c0, u1 = c1;
        bool val1 = (p + 1 < end);
        if (p + 2 < end) {
            int j0 = ssrc[p + 2];
            int j1 = ssrc[(p + 3 < end) ? p + 3 : p + 2];
            c0 = zrp[(size_t)j0 * 128 + lane];
            c1 = zrp[(size_t)j1 * 128 + lane];
        }
        float z00, z01, z02, z03, z10, z11, z12, z13;
        b2f2(u0.x, z00, z01); b2f2(u0.y, z02, z03);
        b2f2(u1.x, z10, z11); b2f2(u1.y, z12, z13);

        float v0 = zl0 + z00, v1 = zl1 + z01, v2 = zl2 + z02, v3 = zl3 + z03;
        float t0 = zl0 + z10, t1 = zl1 + z11, t2 = zl2 + z12, t3 = zl3 + z13;
        v0 = (v0 > 0.f) ? v0 : 0.2f * v0;
        v1 = (v1 > 0.f) ? v1 : 0.2f * v1;
        v2 = (v2 > 0.f) ? v2 : 0.2f * v2;
        v3 = (v3 > 0.f) ? v3 : 0.2f * v3;
        t0 = (t0 > 0.f) ? t0 : 0.2f * t0;
        t1 = (t1 > 0.f) ? t1 : 0.2f * t1;
        t2 = (t2 > 0.f) ? t2 : 0.2f * t2;
        t3 = (t3 > 0.f) ? t3 : 0.2f * t3;
        float part0 = a4.x * v0 + a4.y * v1 + a4.z * v2 + a4.w * v3;
        float part1 = a4.x * t0 + a4.y * t1 + a4.z * t2 + a4.w * t3;
        float sp0 = quad16_sum(part0);      // per-head (quad) score
        float sp1 = quad16_sum(part1);
        if (!val1) sp1 = -3.0e38f;          // sentinel: weight underflows to 0
        float newm = fmaxf(m, fmaxf(sp0, sp1));
        float corr = __expf(m - newm);      // 0 on first pair
        float w0 = __expf(sp0 - newm);
        float w1 = __expf(sp1 - newm);
        denom = denom * corr + w0 + w1;
        ax = ax * corr + w0 * z00 + w1 * z10;
        ay = ay * corr + w0 * z01 + w1 * z11;
        az = az * corr + w0 * z02 + w1 * z12;
        aw = aw * corr + w0 * z03 + w1 * z13;
        m = newm;
    }
    float inv = 1.0f / (denom + 1e-9f);
    float4 o;
    o.x = ax * inv + rres.x;
    o.y = ay * inv + rres.y;
    o.z = az * inv + rres.z;
    o.w = aw * inv + rres.w;
    float sum = wave_sum(o.x + o.y + o.z + o.w);
    float sq  = wave_sum(o.x * o.x + o.y * o.y + o.z * o.z + o.w * o.w);
    float mean = sum * (1.0f / DHID);
    float var  = sq * (1.0f / DHID) - mean * mean;
    float rr = rsqrtf(fmaxf(var, 0.0f) + 1e-3f);
    float4 gv = *(const float4*)(g + lane * 4);
    float4 bv = *(const float4*)(b + lane * 4);
    float4 y;
    y.x = (o.x - mean) * rr * gv.x + bv.x;
    y.y = (o.y - mean) * rr * gv.y + bv.y;
    y.z = (o.z - mean) * rr * gv.z + bv.z;
    y.w = (o.w - mean) * rr * gv.w + bv.w;
    *(float4*)(xr + idx) = y;
    ushort4 ob;
    ob.x = f2b(y.x); ob.y = f2b(y.y); ob.z = f2b(y.z); ob.w = f2b(y.w);
    *(ushort4*)(xrb + idx) = ob;
}

// ---------------------------------------------------------------- host

extern "C" void kernel_launch(void* const* d_in, const int* in_sizes, int n_in,
                              void* d_out, int out_size, void* d_ws, size_t ws_size,
                              hipStream_t stream) {
    const float* x       = (const float*)d_in[0];
    const float* head_W  = (const float*)d_in[1];
    const float* head_b  = (const float*)d_in[2];
    const float* ng_g    = (const float*)d_in[3];
    const float* ng_b    = (const float*)d_in[4];
    const float* Wl      = (const float*)d_in[5];
    const float* Wr      = (const float*)d_in[6];
    const float* att     = (const float*)d_in[7];
    const float* nd_g    = (const float*)d_in[8];
    const float* nd_b    = (const float*)d_in[9];
    const float* dense_W = (const float*)d_in[10];
    const float* dense_b = (const float*)d_in[11];
    const float* tail_W  = (const float*)d_in[12];
    const float* tail_b  = (const float*)d_in[13];
    const int*   edges   = (const int*)d_in[14];
    float* out = (float*)d_out;

    const size_t NH = (size_t)NN * DHID;  // 5,120,000
    // ---- workspace layout (liveness-checked; zb/d union is deliberate) ----
    float* xr = (float*)d_ws;                           // NH f32
    float* hn = xr + NH;                                // NH f32
    unsigned short* hnb = (unsigned short*)(hn + NH);   // NH bf16
    unsigned short* xrb = hnb + NH;                     // NH bf16
    unsigned short* U   = xrb + NH;                     // union region, 4*NH shorts
    unsigned short* zb  = U;                            //   N x 512 bf16  (dies at gat_fused)
    unsigned short* d_buf = U;                          //   N x 1024 bf16 (written after gat_fused)
    unsigned short* headT  = U + 4 * NH;
    unsigned short* WzT    = headT + 65536;             // 4 x (512 x 256)
    unsigned short* denseT = WzT + 524288;              // 4 x (1024 x 256)
    unsigned short* tailT  = denseT + 1048576;          // 64 x 256
    int* counts = (int*)(tailT + 16384);
    int* bsums  = counts + NN;
    int* excl   = bsums + 32;
    int* indptr = excl + NN;
    int* cursor = indptr + NN + 1;
    int* ssrc   = cursor + NN;

    // CSR build
    hipMemsetAsync(counts, 0, NN * sizeof(int), stream);
    hist_kernel<<<(EE + 255) / 256, 256, 0, stream>>>(edges, counts, EE);
    scan_block<<<(NN + 1023) / 1024, 1024, 0, stream>>>(counts, excl, bsums, NN);
    scan_tops<<<1, 64, 0, stream>>>(bsums, (NN + 1023) / 1024);
    scan_fix<<<(NN + 255) / 256, 256, 0, stream>>>(excl, bsums, indptr, cursor, NN);
    scatter_kernel<<<(EE + 255) / 256, 256, 0, stream>>>(edges, cursor, ssrc, EE);

    // weight prep
    transpose_bf16<<<dim3(8, 8, 1), 256, 0, stream>>>(head_W, headT, 256, 256, 0, 0);
    transpose_bf16<<<dim3(8, 8, 4), 256, 0, stream>>>(Wl, WzT, 256, 256, 65536, 131072);
    transpose_bf16<<<dim3(8, 8, 4), 256, 0, stream>>>(Wr, WzT + 65536, 256, 256, 65536, 131072);
    transpose_bf16<<<dim3(32, 8, 4), 256, 0, stream>>>(dense_W, denseT, 256, 1024, 262144, 262144);
    transpose_bf16<<<dim3(2, 8, 1), 256, 0, stream>>>(tail_W, tailT, 256, 64, 0, 0);
    convert_bf16<<<(int)(NH / 4 + 255) / 256, 256, 0, stream>>>(x, hnb, (int)(NH / 4));

    const int GXP = 160;  // multiple of 8 -> XCD = bx & 7 for every by
    // head: xr = x @ head_W + head_b (fp32)
    gemm128<0><<<dim3(GXP, 2), 256, 0, stream>>>(hnb, headT, head_b, xr, NN, 256);

    for (int l = 0; l < 4; ++l) {
        if (l == 0)
            ln_kernel<<<NN / 4, 256, 0, stream>>>(xr, ng_g, ng_b, hn, hnb, NN);
        else
            ln_dense<<<NN / 4, 256, 0, stream>>>(d_buf, xr, ng_g + l * 256, ng_b + l * 256, hn, hnb, NN);
        // [zl|zr] = hn @ [Wl|Wr]
        gemm128<1><<<dim3(GXP, 4), 256, 0, stream>>>(hnb, WzT + (size_t)l * 131072, nullptr, zb, NN, 512);
        // fused scores + online-softmax agg + residual + LayerNorm
        gat_fused<<<(NN + 3) / 4, 256, 0, stream>>>(zb, att + l * 256, ssrc, indptr, hn,
                                                    nd_g + l * 256, nd_b + l * 256, xr, xrb, NN);
        // d = gelu(xr @ dense_W + dense_b)  (partial chunks, bf16) — clobbers zb (dead)
        gemm128<2><<<dim3(GXP, 8), 256, 0, stream>>>(xrb, denseT + (size_t)l * 262144,
                                                     dense_b + l * 1024, d_buf, NN, 1024);
    }
    // hb = bf16(sum_c d + xr) -> hnb (dead); out = hb @ tail_W + tail_b
    combine_final<<<NN / 4, 256, 0, stream>>>(d_buf, xr, hnb, NN);
    gemm128<0><<<dim3(GXP, 1), 256, 0, stream>>>(hnb, tailT, tail_b, out, NN, 64);
}

// Round 14
// 636.166 us; speedup vs baseline: 1.2471x; 1.0051x over previous
//
#include <hip/hip_runtime.h>
#include <cstdint>

#define NN 20000
#define EE 320000
#define DHID 256

typedef short bf16x8 __attribute__((ext_vector_type(8)));
typedef float f32x4 __attribute__((ext_vector_type(4)));

// ---------------------------------------------------------------- utilities

__device__ __forceinline__ float b2f(unsigned short u) {
    union { unsigned int i; float f; } v;
    v.i = ((unsigned int)u) << 16;
    return v.f;
}

__device__ __forceinline__ void b2f2(unsigned int w, float& lo, float& hi) {
    union { unsigned int i; float f; } a, c;
    a.i = w << 16;
    c.i = w & 0xffff0000u;
    lo = a.f;
    hi = c.f;
}

__device__ __forceinline__ unsigned short f2b(float x) {
    union { float f; unsigned int i; } v;
    v.f = x;
    unsigned int r = (v.i + 0x7FFFu + ((v.i >> 16) & 1u)) >> 16;
    return (unsigned short)r;
}

__device__ __forceinline__ float wave_sum(float v) {
#pragma unroll
    for (int m = 1; m < 64; m <<= 1) v += __shfl_xor(v, m);
    return v;
}

__device__ __forceinline__ float quad16_sum(float v) {
#pragma unroll
    for (int m = 1; m < 16; m <<= 1) v += __shfl_xor(v, m);
    return v;
}

__device__ __forceinline__ float gelu_f(float x) {
    float z = 0.7978845608028654f * (x + 0.044715f * x * x * x);
    float e = __expf(2.0f * z);
    float t = 1.0f - 2.0f / (e + 1.0f);   // tanh(z)
    return 0.5f * x * (1.0f + t);
}

// async global->LDS, 16B per lane; lds dest is wave-uniform base (+HW lane*16)
__device__ __forceinline__ void gld16(const unsigned short* g, unsigned short* lds) {
    __builtin_amdgcn_global_load_lds((const __attribute__((address_space(1))) unsigned int*)g,
                                     (__attribute__((address_space(3))) unsigned int*)lds, 16, 0, 0);
}

// ---------------------------------------------------------------- CSR build

__global__ void hist_kernel(const int* __restrict__ edges, int* __restrict__ counts, int E_) {
    int e = blockIdx.x * 256 + threadIdx.x;
    if (e >= E_) return;
    atomicAdd(&counts[edges[e * 2]], 1);
}

__global__ __launch_bounds__(1024) void scan_block(const int* __restrict__ counts,
                                                   int* __restrict__ excl,
                                                   int* __restrict__ bsums, int n) {
    __shared__ int sd[1024];
    int tid = threadIdx.x;
    int i = blockIdx.x * 1024 + tid;
    int c = (i < n) ? counts[i] : 0;
    sd[tid] = c;
    __syncthreads();
#pragma unroll
    for (int off = 1; off < 1024; off <<= 1) {
        int v = (tid >= off) ? sd[tid - off] : 0;
        __syncthreads();
        sd[tid] += v;
        __syncthreads();
    }
    if (i < n) excl[i] = sd[tid] - c;
    if (tid == 1023) bsums[blockIdx.x] = sd[1023];
}

__global__ void scan_tops(int* __restrict__ bsums, int nb) {
    if (threadIdx.x == 0 && blockIdx.x == 0) {
        int run = 0;
        for (int i = 0; i < nb; ++i) { int t = bsums[i]; bsums[i] = run; run += t; }
    }
}

__global__ void scan_fix(const int* __restrict__ excl, const int* __restrict__ bsums,
                         int* __restrict__ indptr, int* __restrict__ cursor, int n) {
    int i = blockIdx.x * 256 + threadIdx.x;
    if (i < n) {
        int v = excl[i] + bsums[i >> 10];
        indptr[i] = v;
        cursor[i] = v;
    }
    if (i == 0) indptr[n] = EE;
}

__global__ void scatter_kernel(const int* __restrict__ edges, int* __restrict__ cursor,
                               int* __restrict__ ssrc, int E_) {
    int e = blockIdx.x * 256 + threadIdx.x;
    if (e >= E_) return;
    int dstn = edges[e * 2];
    int src  = edges[e * 2 + 1];
    int pos = atomicAdd(&cursor[dstn], 1);
    ssrc[pos] = src;
}

// ---------------------------------------------------------------- weight transpose: W (K x M) fp32 -> Wt (M x K) bf16

__global__ __launch_bounds__(256) void transpose_bf16(const float* __restrict__ W,
                                                      unsigned short* __restrict__ Wt,
                                                      int K, int M, size_t lsW, size_t lsT) {
    W  += (size_t)blockIdx.z * lsW;
    Wt += (size_t)blockIdx.z * lsT;
    __shared__ float sm[32][33];
    int m0 = blockIdx.x * 32, k0 = blockIdx.y * 32;
    int tx = threadIdx.x & 31, ty = threadIdx.x >> 5;
#pragma unroll
    for (int i = 0; i < 4; ++i)
        sm[ty + i * 8][tx] = W[(size_t)(k0 + ty + i * 8) * M + m0 + tx];
    __syncthreads();
#pragma unroll
    for (int i = 0; i < 4; ++i)
        Wt[(size_t)(m0 + ty + i * 8) * K + k0 + tx] = f2b(sm[tx][ty + i * 8]);
}

__global__ void convert_bf16(const float* __restrict__ in, unsigned short* __restrict__ out, int n4) {
    int i = blockIdx.x * 256 + threadIdx.x;
    if (i >= n4) return;
    float4 v = *(const float4*)(in + (size_t)i * 4);
    ushort4 o;
    o.x = f2b(v.x); o.y = f2b(v.y); o.z = f2b(v.z); o.w = f2b(v.w);
    *(ushort4*)(out + (size_t)i * 4) = o;
}

// ---------------------------------------------------------------- LayerNorm (plain, fp32 in -> fp32 + bf16)

__global__ __launch_bounds__(256) void ln_kernel(const float* __restrict__ X,
                                                 const float* __restrict__ g,
                                                 const float* __restrict__ b,
                                                 float* __restrict__ Y,
                                                 unsigned short* __restrict__ Yb, int nrows) {
    int row = blockIdx.x * 4 + (threadIdx.x >> 6);
    int lane = threadIdx.x & 63;
    if (row >= nrows) return;
    float4 v = *(const float4*)(X + (size_t)row * DHID + lane * 4);
    float sum = wave_sum(v.x + v.y + v.z + v.w);
    float sq  = wave_sum(v.x * v.x + v.y * v.y + v.z * v.z + v.w * v.w);
    float mean = sum * (1.0f / DHID);
    float var  = sq * (1.0f / DHID) - mean * mean;
    float r = rsqrtf(fmaxf(var, 0.0f) + 1e-3f);
    float4 gv = *(const float4*)(g + lane * 4);
    float4 bv = *(const float4*)(b + lane * 4);
    float4 o;
    o.x = (v.x - mean) * r * gv.x + bv.x;
    o.y = (v.y - mean) * r * gv.y + bv.y;
    o.z = (v.z - mean) * r * gv.z + bv.z;
    o.w = (v.w - mean) * r * gv.w + bv.w;
    *(float4*)(Y + (size_t)row * DHID + lane * 4) = o;
    ushort4 ob;
    ob.x = f2b(o.x); ob.y = f2b(o.y); ob.z = f2b(o.z); ob.w = f2b(o.w);
    *(ushort4*)(Yb + (size_t)row * DHID + lane * 4) = ob;
}

// LayerNorm fused with dense-chunk-sum + residual
__global__ __launch_bounds__(256) void ln_dense(const unsigned short* __restrict__ d,
                                                const float* __restrict__ xr,
                                                const float* __restrict__ g,
                                                const float* __restrict__ b,
                                                float* __restrict__ Y,
                                                unsigned short* __restrict__ Yb, int nrows) {
    int row = blockIdx.x * 4 + (threadIdx.x >> 6);
    int lane = threadIdx.x & 63;
    if (row >= nrows) return;
    float4 v = *(const float4*)(xr + (size_t)row * DHID + lane * 4);
#pragma unroll
    for (int c = 0; c < 4; ++c) {
        ushort4 t = *(const ushort4*)(d + (size_t)row * 1024 + c * 256 + lane * 4);
        v.x += b2f(t.x); v.y += b2f(t.y); v.z += b2f(t.z); v.w += b2f(t.w);
    }
    float sum = wave_sum(v.x + v.y + v.z + v.w);
    float sq  = wave_sum(v.x * v.x + v.y * v.y + v.z * v.z + v.w * v.w);
    float mean = sum * (1.0f / DHID);
    float var  = sq * (1.0f / DHID) - mean * mean;
    float r = rsqrtf(fmaxf(var, 0.0f) + 1e-3f);
    float4 gv = *(const float4*)(g + lane * 4);
    float4 bv = *(const float4*)(b + lane * 4);
    float4 o;
    o.x = (v.x - mean) * r * gv.x + bv.x;
    o.y = (v.y - mean) * r * gv.y + bv.y;
    o.z = (v.z - mean) * r * gv.z + bv.z;
    o.w = (v.w - mean) * r * gv.w + bv.w;
    *(float4*)(Y + (size_t)row * DHID + lane * 4) = o;
    ushort4 ob;
    ob.x = f2b(o.x); ob.y = f2b(o.y); ob.z = f2b(o.z); ob.w = f2b(o.w);
    *(ushort4*)(Yb + (size_t)row * DHID + lane * 4) = ob;
}

// final combine (no LN): hb = bf16(sum_c d + xr)
__global__ __launch_bounds__(256) void combine_final(const unsigned short* __restrict__ d,
                                                     const float* __restrict__ xr,
                                                     unsigned short* __restrict__ hb, int nrows) {
    int row = blockIdx.x * 4 + (threadIdx.x >> 6);
    int lane = threadIdx.x & 63;
    if (row >= nrows) return;
    float4 v = *(const float4*)(xr + (size_t)row * DHID + lane * 4);
#pragma unroll
    for (int c = 0; c < 4; ++c) {
        ushort4 t = *(const ushort4*)(d + (size_t)row * 1024 + c * 256 + lane * 4);
        v.x += b2f(t.x); v.y += b2f(t.y); v.z += b2f(t.z); v.w += b2f(t.w);
    }
    ushort4 ob;
    ob.x = f2b(v.x); ob.y = f2b(v.y); ob.z = f2b(v.z); ob.w = f2b(v.w);
    *(ushort4*)(hb + (size_t)row * DHID + lane * 4) = ob;
}

// ---------------------------------------------------------------- MFMA GEMM, 128x128 tile, BK=64 (half the barrier drains vs BK=32)
// A: nrows x 256 bf16 (k contig); B: ncols x 256 bf16 (k contig, i.e. W^T)
// EP: 0 = fp32 out (+bias), 1 = bf16 out, 2 = bf16 gelu(acc + bias)
// Grid-x padded to multiple of 8 -> XCD = bx & 7 for all by (A fetched once).
// LDS: As/Bs (32 KB, K-loop) union Cs (128x140 = 35.8 KB, epilogue only).

#define CS_STRIDE 140  // 128 + 12 shorts

template <int EP>
__global__ __launch_bounds__(256, 3) void gemm128(const unsigned short* __restrict__ A,
                                                  const unsigned short* __restrict__ B,
                                                  const float* __restrict__ bias,
                                                  void* __restrict__ Cv, int nrows, int ncols) {
    __shared__ unsigned short smem[128 * CS_STRIDE];  // 35840 B; >= As(16KB)+Bs(16KB)
    unsigned short* As = smem;                        // 8192 shorts (128 rows x 64 k)
    unsigned short* Bs = smem + 8192;                 // 8192 shorts (128 cols x 64 k)
    unsigned short* Cs = smem;                        // epilogue alias (after final barrier)
    const int bm = blockIdx.x * 128, bn = blockIdx.y * 128;
    if (bm >= nrows) return;  // grid-x padding
    const int tid  = threadIdx.x;
    const int w    = tid >> 6, lane = tid & 63;
    const int quad = lane >> 4, l16 = lane & 15;
    const int wm = w >> 1, wn = w & 1;

    const int srow = lane & 15;
    const int sg   = lane >> 4;   // 0..3
    int ga0 = min(bm + w * 32 + srow,      nrows - 1);
    int ga1 = min(bm + w * 32 + 16 + srow, nrows - 1);
    int gb0 = min(bn + w * 32 + srow,      ncols - 1);
    int gb1 = min(bn + w * 32 + 16 + srow, ncols - 1);
    const unsigned short* Ap0 = A + (size_t)ga0 * 256 + sg * 8;
    const unsigned short* Ap1 = A + (size_t)ga1 * 256 + sg * 8;
    const unsigned short* Bp0 = B + (size_t)gb0 * 256 + sg * 8;
    const unsigned short* Bp1 = B + (size_t)gb1 * 256 + sg * 8;
    unsigned short* la0 = As + (2 * w) * 1024;
    unsigned short* la1 = As + (2 * w + 1) * 1024;
    unsigned short* lb0 = Bs + (2 * w) * 1024;
    unsigned short* lb1 = Bs + (2 * w + 1) * 1024;

    f32x4 acc[4][4] = {};
    for (int k0 = 0; k0 < 256; k0 += 64) {
        gld16(Ap0 + k0,      la0);
        gld16(Ap0 + k0 + 32, la0 + 512);
        gld16(Ap1 + k0,      la1);
        gld16(Ap1 + k0 + 32, la1 + 512);
        gld16(Bp0 + k0,      lb0);
        gld16(Bp0 + k0 + 32, lb0 + 512);
        gld16(Bp1 + k0,      lb1);
        gld16(Bp1 + k0 + 32, lb1 + 512);
        __syncthreads();
#pragma unroll
        for (int kk = 0; kk < 2; ++kk) {
            bf16x8 a[4], b[4];
#pragma unroll
            for (int mi = 0; mi < 4; ++mi)
                a[mi] = *(const bf16x8*)(As + (wm * 4 + mi) * 1024 + (kk * 4 + quad) * 128 + l16 * 8);
#pragma unroll
            for (int ni = 0; ni < 4; ++ni)
                b[ni] = *(const bf16x8*)(Bs + (wn * 4 + ni) * 1024 + (kk * 4 + quad) * 128 + l16 * 8);
#pragma unroll
            for (int mi = 0; mi < 4; ++mi)
#pragma unroll
                for (int ni = 0; ni < 4; ++ni)
                    acc[mi][ni] = __builtin_amdgcn_mfma_f32_16x16x32_bf16(a[mi], b[ni], acc[mi][ni], 0, 0, 0);
        }
        __syncthreads();
    }

    if (EP == 0) {
        // fp32 out (head/tail): direct stores
#pragma unroll
        for (int ni = 0; ni < 4; ++ni) {
            int col = bn + wn * 64 + ni * 16 + l16;
            if (col >= ncols) continue;
            float bv = bias ? bias[col] : 0.0f;
#pragma unroll
            for (int mi = 0; mi < 4; ++mi) {
#pragma unroll
                for (int r = 0; r < 4; ++r) {
                    int row = bm + wm * 64 + mi * 16 + quad * 4 + r;
                    if (row < nrows) ((float*)Cv)[(size_t)row * ncols + col] = acc[mi][ni][r] + bv;
                }
            }
        }
    } else {
        // bf16 out: stage tile in Cs (aliases As/Bs, dead after K-loop), coalesced 16B stores
#pragma unroll
        for (int ni = 0; ni < 4; ++ni) {
            int lc = wn * 64 + ni * 16 + l16;
            float bv = (EP == 2) ? bias[bn + lc] : 0.0f;
#pragma unroll
            for (int mi = 0; mi < 4; ++mi) {
#pragma unroll
                for (int r = 0; r < 4; ++r) {
                    int lr = wm * 64 + mi * 16 + quad * 4 + r;
                    float v = acc[mi][ni][r] + bv;
                    Cs[lr * CS_STRIDE + lc] = f2b(EP == 2 ? gelu_f(v) : v);
                }
            }
        }
        __syncthreads();
#pragma unroll
        for (int i = 0; i < 8; ++i) {
            int id = tid + 256 * i;          // 0..2047
            int lr = id >> 4;                // 0..127
            int lc = (id & 15) * 8;          // 0..120
            int grow = bm + lr;
            if (grow < nrows) {
                uint4 val = *(const uint4*)(Cs + lr * CS_STRIDE + lc);
                *(uint4*)((unsigned short*)Cv + (size_t)grow * ncols + bn + lc) = val;
            }
        }
    }
}

// ---------------------------------------------------------------- fused GAT edge phase
// Plain-exp softmax (no running max): scores are O(1) magnitude (att ~ 1/8-scaled,
// zl/zr ~ N(0,1) post-LN), |s| << 88, so exp(s) cannot overflow fp32. Removing the
// max kills the loop-carried serial chain; mathematically identical result.

__global__ __launch_bounds__(256) void gat_fused(const unsigned short* __restrict__ zb,
                                                 const float* __restrict__ att,
                                                 const int* __restrict__ ssrc,
                                                 const int* __restrict__ indptr,
                                                 const float* __restrict__ hn,
                                                 const float* __restrict__ g,
                                                 const float* __restrict__ b,
                                                 float* __restrict__ xr,
                                                 unsigned short* __restrict__ xrb, int nrows) {
    int wid = threadIdx.x >> 6;
    int lane = threadIdx.x & 63;
    int n = blockIdx.x * 4 + wid;
    if (n >= nrows) return;
    int start = indptr[n];
    int end = indptr[n + 1];

    ushort4 zlu = *(const ushort4*)(zb + (size_t)n * 512 + lane * 4);
    float zl0 = b2f(zlu.x), zl1 = b2f(zlu.y), zl2 = b2f(zlu.z), zl3 = b2f(zlu.w);
    float4 a4 = *(const float4*)(att + lane * 4);
    size_t idx = (size_t)n * DHID + lane * 4;
    float4 rres = *(const float4*)(hn + idx);

    float denom = 0.f;
    float ax = 0.f, ay = 0.f, az = 0.f, aw = 0.f;

    const uint2* zrp = (const uint2*)(zb + 256);  // row n: zrp[n*128 + lane]
    uint2 c0 = make_uint2(0, 0), c1 = make_uint2(0, 0);
    if (start < end) {
        int i0 = ssrc[start];
        int i1 = ssrc[(start + 1 < end) ? start + 1 : start];
        c0 = zrp[(size_t)i0 * 128 + lane];
        c1 = zrp[(size_t)i1 * 128 + lane];
    }
    for (int p = start; p < end; p += 2) {
        uint2 u0 = c0, u1 = c1;
        bool val1 = (p + 1 < end);
        if (p + 2 < end) {
            int j0 = ssrc[p + 2];
            int j1 = ssrc[(p + 3 < end) ? p + 3 : p + 2];
            c0 = zrp[(size_t)j0 * 128 + lane];
            c1 = zrp[(size_t)j1 * 128 + lane];
        }
        float z00, z01, z02, z03, z10, z11, z12, z13;
        b2f2(u0.x, z00, z01); b2f2(u0.y, z02, z03);
        b2f2(u1.x, z10, z11); b2f2(u1.y, z12, z13);

        float v0 = zl0 + z00, v1 = zl1 + z01, v2 = zl2 + z02, v3 = zl3 + z03;
        float t0 = zl0 + z10, t1 = zl1 + z11, t2 = zl2 + z12, t3 = zl3 + z13;
        v0 = (v0 > 0.f) ? v0 : 0.2f * v0;
        v1 = (v1 > 0.f) ? v1 : 0.2f * v1;
        v2 = (v2 > 0.f) ? v2 : 0.2f * v2;
        v3 = (v3 > 0.f) ? v3 : 0.2f * v3;
        t0 = (t0 > 0.f) ? t0 : 0.2f * t0;
        t1 = (t1 > 0.f) ? t1 : 0.2f * t1;
        t2 = (t2 > 0.f) ? t2 : 0.2f * t2;
        t3 = (t3 > 0.f) ? t3 : 0.2f * t3;
        float part0 = a4.x * v0 + a4.y * v1 + a4.z * v2 + a4.w * v3;
        float part1 = a4.x * t0 + a4.y * t1 + a4.z * t2 + a4.w * t3;
        float sp0 = quad16_sum(part0);      // per-head (quad) score
        float sp1 = quad16_sum(part1);
        float w0 = __expf(sp0);
        float w1 = val1 ? __expf(sp1) : 0.0f;
        denom += w0 + w1;
        ax += w0 * z00 + w1 * z10;
        ay += w0 * z01 + w1 * z11;
        az += w0 * z02 + w1 * z12;
        aw += w0 * z03 + w1 * z13;
    }
    float inv = 1.0f / (denom + 1e-9f);
    float4 o;
    o.x = ax * inv + rres.x;
    o.y = ay * inv + rres.y;
    o.z = az * inv + rres.z;
    o.w = aw * inv + rres.w;
    float sum = wave_sum(o.x + o.y + o.z + o.w);
    float sq  = wave_sum(o.x * o.x + o.y * o.y + o.z * o.z + o.w * o.w);
    float mean = sum * (1.0f / DHID);
    float var  = sq * (1.0f / DHID) - mean * mean;
    float rr = rsqrtf(fmaxf(var, 0.0f) + 1e-3f);
    float4 gv = *(const float4*)(g + lane * 4);
    float4 bv = *(const float4*)(b + lane * 4);
    float4 y;
    y.x = (o.x - mean) * rr * gv.x + bv.x;
    y.y = (o.y - mean) * rr * gv.y + bv.y;
    y.z = (o.z - mean) * rr * gv.z + bv.z;
    y.w = (o.w - mean) * rr * gv.w + bv.w;
    *(float4*)(xr + idx) = y;
    ushort4 ob;
    ob.x = f2b(y.x); ob.y = f2b(y.y); ob.z = f2b(y.z); ob.w = f2b(y.w);
    *(ushort4*)(xrb + idx) = ob;
}

// ---------------------------------------------------------------- host

extern "C" void kernel_launch(void* const* d_in, const int* in_sizes, int n_in,
                              void* d_out, int out_size, void* d_ws, size_t ws_size,
                              hipStream_t stream) {
    const float* x       = (const float*)d_in[0];
    const float* head_W  = (const float*)d_in[1];
    const float* head_b  = (const float*)d_in[2];
    const float* ng_g    = (const float*)d_in[3];
    const float* ng_b    = (const float*)d_in[4];
    const float* Wl      = (const float*)d_in[5];
    const float* Wr      = (const float*)d_in[6];
    const float* att     = (const float*)d_in[7];
    const float* nd_g    = (const float*)d_in[8];
    const float* nd_b    = (const float*)d_in[9];
    const float* dense_W = (const float*)d_in[10];
    const float* dense_b = (const float*)d_in[11];
    const float* tail_W  = (const float*)d_in[12];
    const float* tail_b  = (const float*)d_in[13];
    const int*   edges   = (const int*)d_in[14];
    float* out = (float*)d_out;

    const size_t NH = (size_t)NN * DHID;  // 5,120,000
    // ---- workspace layout (liveness-checked; zb/d union is deliberate) ----
    float* xr = (float*)d_ws;                           // NH f32
    float* hn = xr + NH;                                // NH f32
    unsigned short* hnb = (unsigned short*)(hn + NH);   // NH bf16
    unsigned short* xrb = hnb + NH;                     // NH bf16
    unsigned short* U   = xrb + NH;                     // union region, 4*NH shorts
    unsigned short* zb  = U;                            //   N x 512 bf16  (dies at gat_fused)
    unsigned short* d_buf = U;                          //   N x 1024 bf16 (written after gat_fused)
    unsigned short* headT  = U + 4 * NH;
    unsigned short* WzT    = headT + 65536;             // 4 x (512 x 256)
    unsigned short* denseT = WzT + 524288;              // 4 x (1024 x 256)
    unsigned short* tailT  = denseT + 1048576;          // 64 x 256
    int* counts = (int*)(tailT + 16384);
    int* bsums  = counts + NN;
    int* excl   = bsums + 32;
    int* indptr = excl + NN;
    int* cursor = indptr + NN + 1;
    int* ssrc   = cursor + NN;

    // CSR build
    hipMemsetAsync(counts, 0, NN * sizeof(int), stream);
    hist_kernel<<<(EE + 255) / 256, 256, 0, stream>>>(edges, counts, EE);
    scan_block<<<(NN + 1023) / 1024, 1024, 0, stream>>>(counts, excl, bsums, NN);
    scan_tops<<<1, 64, 0, stream>>>(bsums, (NN + 1023) / 1024);
    scan_fix<<<(NN + 255) / 256, 256, 0, stream>>>(excl, bsums, indptr, cursor, NN);
    scatter_kernel<<<(EE + 255) / 256, 256, 0, stream>>>(edges, cursor, ssrc, EE);

    // weight prep
    transpose_bf16<<<dim3(8, 8, 1), 256, 0, stream>>>(head_W, headT, 256, 256, 0, 0);
    transpose_bf16<<<dim3(8, 8, 4), 256, 0, stream>>>(Wl, WzT, 256, 256, 65536, 131072);
    transpose_bf16<<<dim3(8, 8, 4), 256, 0, stream>>>(Wr, WzT + 65536, 256, 256, 65536, 131072);
    transpose_bf16<<<dim3(32, 8, 4), 256, 0, stream>>>(dense_W, denseT, 256, 1024, 262144, 262144);
    transpose_bf16<<<dim3(2, 8, 1), 256, 0, stream>>>(tail_W, tailT, 256, 64, 0, 0);
    convert_bf16<<<(int)(NH / 4 + 255) / 256, 256, 0, stream>>>(x, hnb, (int)(NH / 4));

    const int GXP = 160;  // multiple of 8 -> XCD = bx & 7 for every by
    // head: xr = x @ head_W + head_b (fp32)
    gemm128<0><<<dim3(GXP, 2), 256, 0, stream>>>(hnb, headT, head_b, xr, NN, 256);

    for (int l = 0; l < 4; ++l) {
        if (l == 0)
            ln_kernel<<<NN / 4, 256, 0, stream>>>(xr, ng_g, ng_b, hn, hnb, NN);
        else
            ln_dense<<<NN / 4, 256, 0, stream>>>(d_buf, xr, ng_g + l * 256, ng_b + l * 256, hn, hnb, NN);
        // [zl|zr] = hn @ [Wl|Wr]
        gemm128<1><<<dim3(GXP, 4), 256, 0, stream>>>(hnb, WzT + (size_t)l * 131072, nullptr, zb, NN, 512);
        // fused scores + plain-exp softmax agg + residual + LayerNorm
        gat_fused<<<(NN + 3) / 4, 256, 0, stream>>>(zb, att + l * 256, ssrc, indptr, hn,
                                                    nd_g + l * 256, nd_b + l * 256, xr, xrb, NN);
        // d = gelu(xr @ dense_W + dense_b)  (partial chunks, bf16) — clobbers zb (dead)
        gemm128<2><<<dim3(GXP, 8), 256, 0, stream>>>(xrb, denseT + (size_t)l * 262144,
                                                     dense_b + l * 1024, d_buf, NN, 1024);
    }
    // hb = bf16(sum_c d + xr) -> hnb (dead); out = hb @ tail_W + tail_b
    combine_final<<<NN / 4, 256, 0, stream>>>(d_buf, xr, hnb, NN);
    gemm128<0><<<dim3(GXP, 1), 256, 0, stream>>>(hnb, tailT, tail_b, out, NN, 64);
}

// Round 15
// 614.263 us; speedup vs baseline: 1.2916x; 1.0357x over previous
//
#include <hip/hip_runtime.h>
#include <cstdint>

#define NN 20000
#define EE 320000
#define DHID 256

typedef short bf16x8 __attribute__((ext_vector_type(8)));
typedef float f32x4 __attribute__((ext_vector_type(4)));

// ---------------------------------------------------------------- utilities

__device__ __forceinline__ float b2f(unsigned short u) {
    union { unsigned int i; float f; } v;
    v.i = ((unsigned int)u) << 16;
    return v.f;
}

__device__ __forceinline__ void b2f2(unsigned int w, float& lo, float& hi) {
    union { unsigned int i; float f; } a, c;
    a.i = w << 16;
    c.i = w & 0xffff0000u;
    lo = a.f;
    hi = c.f;
}

__device__ __forceinline__ unsigned short f2b(float x) {
    union { float f; unsigned int i; } v;
    v.f = x;
    unsigned int r = (v.i + 0x7FFFu + ((v.i >> 16) & 1u)) >> 16;
    return (unsigned short)r;
}

__device__ __forceinline__ float wave_sum(float v) {
#pragma unroll
    for (int m = 1; m < 64; m <<= 1) v += __shfl_xor(v, m);
    return v;
}

__device__ __forceinline__ float quad16_sum(float v) {
#pragma unroll
    for (int m = 1; m < 16; m <<= 1) v += __shfl_xor(v, m);
    return v;
}

__device__ __forceinline__ float gelu_f(float x) {
    float z = 0.7978845608028654f * (x + 0.044715f * x * x * x);
    float e = __expf(2.0f * z);
    float t = 1.0f - 2.0f / (e + 1.0f);   // tanh(z)
    return 0.5f * x * (1.0f + t);
}

// async global->LDS, 16B per lane; lds dest is wave-uniform base (+HW lane*16)
__device__ __forceinline__ void gld16(const unsigned short* g, unsigned short* lds) {
    __builtin_amdgcn_global_load_lds((const __attribute__((address_space(1))) unsigned int*)g,
                                     (__attribute__((address_space(3))) unsigned int*)lds, 16, 0, 0);
}

// ---------------------------------------------------------------- CSR build

__global__ void hist_kernel(const int* __restrict__ edges, int* __restrict__ counts, int E_) {
    int e = blockIdx.x * 256 + threadIdx.x;
    if (e >= E_) return;
    atomicAdd(&counts[edges[e * 2]], 1);
}

__global__ __launch_bounds__(1024) void scan_block(const int* __restrict__ counts,
                                                   int* __restrict__ excl,
                                                   int* __restrict__ bsums, int n) {
    __shared__ int sd[1024];
    int tid = threadIdx.x;
    int i = blockIdx.x * 1024 + tid;
    int c = (i < n) ? counts[i] : 0;
    sd[tid] = c;
    __syncthreads();
#pragma unroll
    for (int off = 1; off < 1024; off <<= 1) {
        int v = (tid >= off) ? sd[tid - off] : 0;
        __syncthreads();
        sd[tid] += v;
        __syncthreads();
    }
    if (i < n) excl[i] = sd[tid] - c;
    if (tid == 1023) bsums[blockIdx.x] = sd[1023];
}

__global__ void scan_tops(int* __restrict__ bsums, int nb) {
    if (threadIdx.x == 0 && blockIdx.x == 0) {
        int run = 0;
        for (int i = 0; i < nb; ++i) { int t = bsums[i]; bsums[i] = run; run += t; }
    }
}

__global__ void scan_fix(const int* __restrict__ excl, const int* __restrict__ bsums,
                         int* __restrict__ indptr, int* __restrict__ cursor, int n) {
    int i = blockIdx.x * 256 + threadIdx.x;
    if (i < n) {
        int v = excl[i] + bsums[i >> 10];
        indptr[i] = v;
        cursor[i] = v;
    }
    if (i == 0) indptr[n] = EE;
}

__global__ void scatter_kernel(const int* __restrict__ edges, int* __restrict__ cursor,
                               int* __restrict__ ssrc, int E_) {
    int e = blockIdx.x * 256 + threadIdx.x;
    if (e >= E_) return;
    int dstn = edges[e * 2];
    int src  = edges[e * 2 + 1];
    int pos = atomicAdd(&cursor[dstn], 1);
    ssrc[pos] = src;
}

// ---------------------------------------------------------------- weight transpose: W (K x M) fp32 -> Wt (M x K) bf16

__global__ __launch_bounds__(256) void transpose_bf16(const float* __restrict__ W,
                                                      unsigned short* __restrict__ Wt,
                                                      int K, int M, size_t lsW, size_t lsT) {
    W  += (size_t)blockIdx.z * lsW;
    Wt += (size_t)blockIdx.z * lsT;
    __shared__ float sm[32][33];
    int m0 = blockIdx.x * 32, k0 = blockIdx.y * 32;
    int tx = threadIdx.x & 31, ty = threadIdx.x >> 5;
#pragma unroll
    for (int i = 0; i < 4; ++i)
        sm[ty + i * 8][tx] = W[(size_t)(k0 + ty + i * 8) * M + m0 + tx];
    __syncthreads();
#pragma unroll
    for (int i = 0; i < 4; ++i)
        Wt[(size_t)(m0 + ty + i * 8) * K + k0 + tx] = f2b(sm[tx][ty + i * 8]);
}

__global__ void convert_bf16(const float* __restrict__ in, unsigned short* __restrict__ out, int n4) {
    int i = blockIdx.x * 256 + threadIdx.x;
    if (i >= n4) return;
    float4 v = *(const float4*)(in + (size_t)i * 4);
    ushort4 o;
    o.x = f2b(v.x); o.y = f2b(v.y); o.z = f2b(v.z); o.w = f2b(v.w);
    *(ushort4*)(out + (size_t)i * 4) = o;
}

// ---------------------------------------------------------------- LayerNorm (plain, fp32 in -> fp32 + bf16)

__global__ __launch_bounds__(256) void ln_kernel(const float* __restrict__ X,
                                                 const float* __restrict__ g,
                                                 const float* __restrict__ b,
                                                 float* __restrict__ Y,
                                                 unsigned short* __restrict__ Yb, int nrows) {
    int row = blockIdx.x * 4 + (threadIdx.x >> 6);
    int lane = threadIdx.x & 63;
    if (row >= nrows) return;
    float4 v = *(const float4*)(X + (size_t)row * DHID + lane * 4);
    float sum = wave_sum(v.x + v.y + v.z + v.w);
    float sq  = wave_sum(v.x * v.x + v.y * v.y + v.z * v.z + v.w * v.w);
    float mean = sum * (1.0f / DHID);
    float var  = sq * (1.0f / DHID) - mean * mean;
    float r = rsqrtf(fmaxf(var, 0.0f) + 1e-3f);
    float4 gv = *(const float4*)(g + lane * 4);
    float4 bv = *(const float4*)(b + lane * 4);
    float4 o;
    o.x = (v.x - mean) * r * gv.x + bv.x;
    o.y = (v.y - mean) * r * gv.y + bv.y;
    o.z = (v.z - mean) * r * gv.z + bv.z;
    o.w = (v.w - mean) * r * gv.w + bv.w;
    *(float4*)(Y + (size_t)row * DHID + lane * 4) = o;
    ushort4 ob;
    ob.x = f2b(o.x); ob.y = f2b(o.y); ob.z = f2b(o.z); ob.w = f2b(o.w);
    *(ushort4*)(Yb + (size_t)row * DHID + lane * 4) = ob;
}

// LayerNorm fused with dense-chunk-sum + residual
__global__ __launch_bounds__(256) void ln_dense(const unsigned short* __restrict__ d,
                                                const float* __restrict__ xr,
                                                const float* __restrict__ g,
                                                const float* __restrict__ b,
                                                float* __restrict__ Y,
                                                unsigned short* __restrict__ Yb, int nrows) {
    int row = blockIdx.x * 4 + (threadIdx.x >> 6);
    int lane = threadIdx.x & 63;
    if (row >= nrows) return;
    float4 v = *(const float4*)(xr + (size_t)row * DHID + lane * 4);
#pragma unroll
    for (int c = 0; c < 4; ++c) {
        ushort4 t = *(const ushort4*)(d + (size_t)row * 1024 + c * 256 + lane * 4);
        v.x += b2f(t.x); v.y += b2f(t.y); v.z += b2f(t.z); v.w += b2f(t.w);
    }
    float sum = wave_sum(v.x + v.y + v.z + v.w);
    float sq  = wave_sum(v.x * v.x + v.y * v.y + v.z * v.z + v.w * v.w);
    float mean = sum * (1.0f / DHID);
    float var  = sq * (1.0f / DHID) - mean * mean;
    float r = rsqrtf(fmaxf(var, 0.0f) + 1e-3f);
    float4 gv = *(const float4*)(g + lane * 4);
    float4 bv = *(const float4*)(b + lane * 4);
    float4 o;
    o.x = (v.x - mean) * r * gv.x + bv.x;
    o.y = (v.y - mean) * r * gv.y + bv.y;
    o.z = (v.z - mean) * r * gv.z + bv.z;
    o.w = (v.w - mean) * r * gv.w + bv.w;
    *(float4*)(Y + (size_t)row * DHID + lane * 4) = o;
    ushort4 ob;
    ob.x = f2b(o.x); ob.y = f2b(o.y); ob.z = f2b(o.z); ob.w = f2b(o.w);
    *(ushort4*)(Yb + (size_t)row * DHID + lane * 4) = ob;
}

// final combine (no LN): hb = bf16(sum_c d + xr)
__global__ __launch_bounds__(256) void combine_final(const unsigned short* __restrict__ d,
                                                     const float* __restrict__ xr,
                                                     unsigned short* __restrict__ hb, int nrows) {
    int row = blockIdx.x * 4 + (threadIdx.x >> 6);
    int lane = threadIdx.x & 63;
    if (row >= nrows) return;
    float4 v = *(const float4*)(xr + (size_t)row * DHID + lane * 4);
#pragma unroll
    for (int c = 0; c < 4; ++c) {
        ushort4 t = *(const ushort4*)(d + (size_t)row * 1024 + c * 256 + lane * 4);
        v.x += b2f(t.x); v.y += b2f(t.y); v.z += b2f(t.z); v.w += b2f(t.w);
    }
    ushort4 ob;
    ob.x = f2b(v.x); ob.y = f2b(v.y); ob.z = f2b(v.z); ob.w = f2b(v.w);
    *(ushort4*)(hb + (size_t)row * DHID + lane * 4) = ob;
}

// ---------------------------------------------------------------- MFMA GEMM, 128x128 tile, BK=64
// A: nrows x 256 bf16 (k contig); B: ncols x 256 bf16 (k contig, i.e. W^T)
// EP: 0 = fp32 out (+bias), 1 = bf16 out, 2 = bf16 gelu(acc + bias)
// Grid-x padded to multiple of 8 -> XCD = bx & 7 for all by (A fetched once).
// LDS: As/Bs (32 KB, K-loop) union Cs (128x140 = 35.8 KB, epilogue only).

#define CS_STRIDE 140  // 128 + 12 shorts

template <int EP>
__global__ __launch_bounds__(256, 3) void gemm128(const unsigned short* __restrict__ A,
                                                  const unsigned short* __restrict__ B,
                                                  const float* __restrict__ bias,
                                                  void* __restrict__ Cv, int nrows, int ncols) {
    __shared__ unsigned short smem[128 * CS_STRIDE];  // 35840 B; >= As(16KB)+Bs(16KB)
    unsigned short* As = smem;                        // 8192 shorts (128 rows x 64 k)
    unsigned short* Bs = smem + 8192;                 // 8192 shorts (128 cols x 64 k)
    unsigned short* Cs = smem;                        // epilogue alias (after final barrier)
    const int bm = blockIdx.x * 128, bn = blockIdx.y * 128;
    if (bm >= nrows) return;  // grid-x padding
    const int tid  = threadIdx.x;
    const int w    = tid >> 6, lane = tid & 63;
    const int quad = lane >> 4, l16 = lane & 15;
    const int wm = w >> 1, wn = w & 1;

    const int srow = lane & 15;
    const int sg   = lane >> 4;   // 0..3
    int ga0 = min(bm + w * 32 + srow,      nrows - 1);
    int ga1 = min(bm + w * 32 + 16 + srow, nrows - 1);
    int gb0 = min(bn + w * 32 + srow,      ncols - 1);
    int gb1 = min(bn + w * 32 + 16 + srow, ncols - 1);
    const unsigned short* Ap0 = A + (size_t)ga0 * 256 + sg * 8;
    const unsigned short* Ap1 = A + (size_t)ga1 * 256 + sg * 8;
    const unsigned short* Bp0 = B + (size_t)gb0 * 256 + sg * 8;
    const unsigned short* Bp1 = B + (size_t)gb1 * 256 + sg * 8;
    unsigned short* la0 = As + (2 * w) * 1024;
    unsigned short* la1 = As + (2 * w + 1) * 1024;
    unsigned short* lb0 = Bs + (2 * w) * 1024;
    unsigned short* lb1 = Bs + (2 * w + 1) * 1024;

    f32x4 acc[4][4] = {};
    for (int k0 = 0; k0 < 256; k0 += 64) {
        gld16(Ap0 + k0,      la0);
        gld16(Ap0 + k0 + 32, la0 + 512);
        gld16(Ap1 + k0,      la1);
        gld16(Ap1 + k0 + 32, la1 + 512);
        gld16(Bp0 + k0,      lb0);
        gld16(Bp0 + k0 + 32, lb0 + 512);
        gld16(Bp1 + k0,      lb1);
        gld16(Bp1 + k0 + 32, lb1 + 512);
        __syncthreads();
#pragma unroll
        for (int kk = 0; kk < 2; ++kk) {
            bf16x8 a[4], b[4];
#pragma unroll
            for (int mi = 0; mi < 4; ++mi)
                a[mi] = *(const bf16x8*)(As + (wm * 4 + mi) * 1024 + (kk * 4 + quad) * 128 + l16 * 8);
#pragma unroll
            for (int ni = 0; ni < 4; ++ni)
                b[ni] = *(const bf16x8*)(Bs + (wn * 4 + ni) * 1024 + (kk * 4 + quad) * 128 + l16 * 8);
#pragma unroll
            for (int mi = 0; mi < 4; ++mi)
#pragma unroll
                for (int ni = 0; ni < 4; ++ni)
                    acc[mi][ni] = __builtin_amdgcn_mfma_f32_16x16x32_bf16(a[mi], b[ni], acc[mi][ni], 0, 0, 0);
        }
        __syncthreads();
    }

    if (EP == 0) {
        // fp32 out (head/tail): direct stores
#pragma unroll
        for (int ni = 0; ni < 4; ++ni) {
            int col = bn + wn * 64 + ni * 16 + l16;
            if (col >= ncols) continue;
            float bv = bias ? bias[col] : 0.0f;
#pragma unroll
            for (int mi = 0; mi < 4; ++mi) {
#pragma unroll
                for (int r = 0; r < 4; ++r) {
                    int row = bm + wm * 64 + mi * 16 + quad * 4 + r;
                    if (row < nrows) ((float*)Cv)[(size_t)row * ncols + col] = acc[mi][ni][r] + bv;
                }
            }
        }
    } else {
        // bf16 out: stage tile in Cs (aliases As/Bs, dead after K-loop), coalesced 16B stores
#pragma unroll
        for (int ni = 0; ni < 4; ++ni) {
            int lc = wn * 64 + ni * 16 + l16;
            float bv = (EP == 2) ? bias[bn + lc] : 0.0f;
#pragma unroll
            for (int mi = 0; mi < 4; ++mi) {
#pragma unroll
                for (int r = 0; r < 4; ++r) {
                    int lr = wm * 64 + mi * 16 + quad * 4 + r;
                    float v = acc[mi][ni][r] + bv;
                    Cs[lr * CS_STRIDE + lc] = f2b(EP == 2 ? gelu_f(v) : v);
                }
            }
        }
        __syncthreads();
#pragma unroll
        for (int i = 0; i < 8; ++i) {
            int id = tid + 256 * i;          // 0..2047
            int lr = id >> 4;                // 0..127
            int lc = (id & 15) * 8;          // 0..120
            int grow = bm + lr;
            if (grow < nrows) {
                uint4 val = *(const uint4*)(Cs + lr * CS_STRIDE + lc);
                *(uint4*)((unsigned short*)Cv + (size_t)grow * ncols + bn + lc) = val;
            }
        }
    }
}

// ---------------------------------------------------------------- fused GAT edge phase
// Plain-exp softmax (bounded scores, no overflow risk) + 4-edge prefetch ring:
// 2x deeper MLP than the pair version — each wave keeps 4 gathers in flight.

__global__ __launch_bounds__(256) void gat_fused(const unsigned short* __restrict__ zb,
                                                 const float* __restrict__ att,
                                                 const int* __restrict__ ssrc,
                                                 const int* __restrict__ indptr,
                                                 const float* __restrict__ hn,
                                                 const float* __restrict__ g,
                                                 const float* __restrict__ b,
                                                 float* __restrict__ xr,
                                                 unsigned short* __restrict__ xrb, int nrows) {
    int wid = threadIdx.x >> 6;
    int lane = threadIdx.x & 63;
    int n = blockIdx.x * 4 + wid;
    if (n >= nrows) return;
    int start = indptr[n];
    int end = indptr[n + 1];

    ushort4 zlu = *(const ushort4*)(zb + (size_t)n * 512 + lane * 4);
    float zl0 = b2f(zlu.x), zl1 = b2f(zlu.y), zl2 = b2f(zlu.z), zl3 = b2f(zlu.w);
    float4 a4 = *(const float4*)(att + lane * 4);
    size_t idx = (size_t)n * DHID + lane * 4;
    float4 rres = *(const float4*)(hn + idx);

    float denom = 0.f;
    float ax = 0.f, ay = 0.f, az = 0.f, aw = 0.f;

    const uint2* zrp = (const uint2*)(zb + 256);  // row n: zrp[n*128 + lane]
    uint2 c0 = make_uint2(0, 0), c1 = make_uint2(0, 0);
    uint2 c2 = make_uint2(0, 0), c3 = make_uint2(0, 0);
    if (start < end) {
        int e1 = end - 1;
        c0 = zrp[(size_t)ssrc[start] * 128 + lane];
        c1 = zrp[(size_t)ssrc[min(start + 1, e1)] * 128 + lane];
        c2 = zrp[(size_t)ssrc[min(start + 2, e1)] * 128 + lane];
        c3 = zrp[(size_t)ssrc[min(start + 3, e1)] * 128 + lane];
    }
    for (int p = start; p < end; p += 2) {
        uint2 u0 = c0, u1 = c1;
        bool val1 = (p + 1 < end);
        // rotate ring and prefetch 2 edges at distance 4
        c0 = c2; c1 = c3;
        if (p + 4 < end) {
            int e1 = end - 1;
            c2 = zrp[(size_t)ssrc[p + 4] * 128 + lane];
            c3 = zrp[(size_t)ssrc[min(p + 5, e1)] * 128 + lane];
        }
        float z00, z01, z02, z03, z10, z11, z12, z13;
        b2f2(u0.x, z00, z01); b2f2(u0.y, z02, z03);
        b2f2(u1.x, z10, z11); b2f2(u1.y, z12, z13);

        float v0 = zl0 + z00, v1 = zl1 + z01, v2 = zl2 + z02, v3 = zl3 + z03;
        float t0 = zl0 + z10, t1 = zl1 + z11, t2 = zl2 + z12, t3 = zl3 + z13;
        v0 = (v0 > 0.f) ? v0 : 0.2f * v0;
        v1 = (v1 > 0.f) ? v1 : 0.2f * v1;
        v2 = (v2 > 0.f) ? v2 : 0.2f * v2;
        v3 = (v3 > 0.f) ? v3 : 0.2f * v3;
        t0 = (t0 > 0.f) ? t0 : 0.2f * t0;
        t1 = (t1 > 0.f) ? t1 : 0.2f * t1;
        t2 = (t2 > 0.f) ? t2 : 0.2f * t2;
        t3 = (t3 > 0.f) ? t3 : 0.2f * t3;
        float part0 = a4.x * v0 + a4.y * v1 + a4.z * v2 + a4.w * v3;
        float part1 = a4.x * t0 + a4.y * t1 + a4.z * t2 + a4.w * t3;
        float sp0 = quad16_sum(part0);      // per-head (quad) score
        float sp1 = quad16_sum(part1);
        float w0 = __expf(sp0);
        float w1 = val1 ? __expf(sp1) : 0.0f;
        denom += w0 + w1;
        ax += w0 * z00 + w1 * z10;
        ay += w0 * z01 + w1 * z11;
        az += w0 * z02 + w1 * z12;
        aw += w0 * z03 + w1 * z13;
    }
    float inv = 1.0f / (denom + 1e-9f);
    float4 o;
    o.x = ax * inv + rres.x;
    o.y = ay * inv + rres.y;
    o.z = az * inv + rres.z;
    o.w = aw * inv + rres.w;
    float sum = wave_sum(o.x + o.y + o.z + o.w);
    float sq  = wave_sum(o.x * o.x + o.y * o.y + o.z * o.z + o.w * o.w);
    float mean = sum * (1.0f / DHID);
    float var  = sq * (1.0f / DHID) - mean * mean;
    float rr = rsqrtf(fmaxf(var, 0.0f) + 1e-3f);
    float4 gv = *(const float4*)(g + lane * 4);
    float4 bv = *(const float4*)(b + lane * 4);
    float4 y;
    y.x = (o.x - mean) * rr * gv.x + bv.x;
    y.y = (o.y - mean) * rr * gv.y + bv.y;
    y.z = (o.z - mean) * rr * gv.z + bv.z;
    y.w = (o.w - mean) * rr * gv.w + bv.w;
    *(float4*)(xr + idx) = y;
    ushort4 ob;
    ob.x = f2b(y.x); ob.y = f2b(y.y); ob.z = f2b(y.z); ob.w = f2b(y.w);
    *(ushort4*)(xrb + idx) = ob;
}

// ---------------------------------------------------------------- host

extern "C" void kernel_launch(void* const* d_in, const int* in_sizes, int n_in,
                              void* d_out, int out_size, void* d_ws, size_t ws_size,
                              hipStream_t stream) {
    const float* x       = (const float*)d_in[0];
    const float* head_W  = (const float*)d_in[1];
    const float* head_b  = (const float*)d_in[2];
    const float* ng_g    = (const float*)d_in[3];
    const float* ng_b    = (const float*)d_in[4];
    const float* Wl      = (const float*)d_in[5];
    const float* Wr      = (const float*)d_in[6];
    const float* att     = (const float*)d_in[7];
    const float* nd_g    = (const float*)d_in[8];
    const float* nd_b    = (const float*)d_in[9];
    const float* dense_W = (const float*)d_in[10];
    const float* dense_b = (const float*)d_in[11];
    const float* tail_W  = (const float*)d_in[12];
    const float* tail_b  = (const float*)d_in[13];
    const int*   edges   = (const int*)d_in[14];
    float* out = (float*)d_out;

    const size_t NH = (size_t)NN * DHID;  // 5,120,000
    // ---- workspace layout (liveness-checked; zb/d union is deliberate) ----
    float* xr = (float*)d_ws;                           // NH f32
    float* hn = xr + NH;                                // NH f32
    unsigned short* hnb = (unsigned short*)(hn + NH);   // NH bf16
    unsigned short* xrb = hnb + NH;                     // NH bf16
    unsigned short* U   = xrb + NH;                     // union region, 4*NH shorts
    unsigned short* zb  = U;                            //   N x 512 bf16  (dies at gat_fused)
    unsigned short* d_buf = U;                          //   N x 1024 bf16 (written after gat_fused)
    unsigned short* headT  = U + 4 * NH;
    unsigned short* WzT    = headT + 65536;             // 4 x (512 x 256)
    unsigned short* denseT = WzT + 524288;              // 4 x (1024 x 256)
    unsigned short* tailT  = denseT + 1048576;          // 64 x 256
    int* counts = (int*)(tailT + 16384);
    int* bsums  = counts + NN;
    int* excl   = bsums + 32;
    int* indptr = excl + NN;
    int* cursor = indptr + NN + 1;
    int* ssrc   = cursor + NN;

    // CSR build
    hipMemsetAsync(counts, 0, NN * sizeof(int), stream);
    hist_kernel<<<(EE + 255) / 256, 256, 0, stream>>>(edges, counts, EE);
    scan_block<<<(NN + 1023) / 1024, 1024, 0, stream>>>(counts, excl, bsums, NN);
    scan_tops<<<1, 64, 0, stream>>>(bsums, (NN + 1023) / 1024);
    scan_fix<<<(NN + 255) / 256, 256, 0, stream>>>(excl, bsums, indptr, cursor, NN);
    scatter_kernel<<<(EE + 255) / 256, 256, 0, stream>>>(edges, cursor, ssrc, EE);

    // weight prep
    transpose_bf16<<<dim3(8, 8, 1), 256, 0, stream>>>(head_W, headT, 256, 256, 0, 0);
    transpose_bf16<<<dim3(8, 8, 4), 256, 0, stream>>>(Wl, WzT, 256, 256, 65536, 131072);
    transpose_bf16<<<dim3(8, 8, 4), 256, 0, stream>>>(Wr, WzT + 65536, 256, 256, 65536, 131072);
    transpose_bf16<<<dim3(32, 8, 4), 256, 0, stream>>>(dense_W, denseT, 256, 1024, 262144, 262144);
    transpose_bf16<<<dim3(2, 8, 1), 256, 0, stream>>>(tail_W, tailT, 256, 64, 0, 0);
    convert_bf16<<<(int)(NH / 4 + 255) / 256, 256, 0, stream>>>(x, hnb, (int)(NH / 4));

    const int GXP = 160;  // multiple of 8 -> XCD = bx & 7 for every by
    // head: xr = x @ head_W + head_b (fp32)
    gemm128<0><<<dim3(GXP, 2), 256, 0, stream>>>(hnb, headT, head_b, xr, NN, 256);

    for (int l = 0; l < 4; ++l) {
        if (l == 0)
            ln_kernel<<<NN / 4, 256, 0, stream>>>(xr, ng_g, ng_b, hn, hnb, NN);
        else
            ln_dense<<<NN / 4, 256, 0, stream>>>(d_buf, xr, ng_g + l * 256, ng_b + l * 256, hn, hnb, NN);
        // [zl|zr] = hn @ [Wl|Wr]
        gemm128<1><<<dim3(GXP, 4), 256, 0, stream>>>(hnb, WzT + (size_t)l * 131072, nullptr, zb, NN, 512);
        // fused scores + plain-exp softmax agg + residual + LayerNorm
        gat_fused<<<(NN + 3) / 4, 256, 0, stream>>>(zb, att + l * 256, ssrc, indptr, hn,
                                                    nd_g + l * 256, nd_b + l * 256, xr, xrb, NN);
        // d = gelu(xr @ dense_W + dense_b)  (partial chunks, bf16) — clobbers zb (dead)
        gemm128<2><<<dim3(GXP, 8), 256, 0, stream>>>(xrb, denseT + (size_t)l * 262144,
                                                     dense_b + l * 1024, d_buf, NN, 1024);
    }
    // hb = bf16(sum_c d + xr) -> hnb (dead); out = hb @ tail_W + tail_b
    combine_final<<<NN / 4, 256, 0, stream>>>(d_buf, xr, hnb, NN);
    gemm128<0><<<dim3(GXP, 1), 256, 0, stream>>>(hnb, tailT, tail_b, out, NN, 64);
}